// Round 2
// baseline (5609.732 us; speedup 1.0000x reference)
//
#include <hip/hip_runtime.h>
#include <hip/hip_bf16.h>

#define B_ 8
#define L_ 1024
#define BL (B_*L_)
#define DENC 128
#define DMAIN 256
#define VOCAB 260
#define NHEADS 4

typedef __hip_bfloat16 bf16;

__device__ __forceinline__ float b2f(bf16 v){ return __bfloat162float(v); }

// ---------------- dtype detector: flag=1 if inputs are bf16, 0 if f32 ----------------
__global__ __launch_bounds__(64) void k_detect(const void* __restrict__ emb, int* __restrict__ flag){
    int lane = threadIdx.x;
    const unsigned short* u = (const unsigned short*)emb;
    int bad = 0;
    #pragma unroll
    for (int j = 0; j < 4; j++){
        unsigned short h = u[lane + 64*j];
        bf16 t = *(const bf16*)&h;
        float v = __bfloat162float(t);
        if (!(fabsf(v) < 1e4f)) bad++;   // huge or NaN => low-half-of-float garbage
    }
    #pragma unroll
    for (int o = 32; o >= 1; o >>= 1) bad += __shfl_xor(bad, o);
    if (lane == 0) flag[0] = (bad == 0) ? 1 : 0;
}

// ---------------- convert any float input to f32 workspace copy ----------------
__global__ void k_cvt(const void* __restrict__ src, float* __restrict__ dst, int n,
                      const int* __restrict__ flag){
    int i = blockIdx.x*256 + threadIdx.x;
    if (i >= n) return;
    if (flag[0]) dst[i] = __bfloat162float(((const bf16*)src)[i]);
    else         dst[i] = ((const float*)src)[i];
}

// ---------------- embed gather ----------------
__global__ void k_embed(const int* __restrict__ ids, const float* __restrict__ emb, float* __restrict__ x){
    int i = blockIdx.x*256 + threadIdx.x;      // over BL*DENC
    int row = i >> 7, d = i & 127;
    x[i] = emb[ids[row]*DENC + d];
}

// ---------------- layernorm (one wave per row) ----------------
template<int D>
__global__ __launch_bounds__(64) void k_ln(const float* __restrict__ x, const float* __restrict__ w,
                                           const float* __restrict__ b, float* __restrict__ y){
    int row = blockIdx.x;
    int lane = threadIdx.x;
    const float* xr = x + (size_t)row*D;
    float v[D/64];
    float s = 0.f;
    #pragma unroll
    for (int j=0;j<D/64;j++){ v[j] = xr[lane + j*64]; s += v[j]; }
    #pragma unroll
    for (int o=32;o>=1;o>>=1) s += __shfl_xor(s,o);
    float mu = s / (float)D;
    float s2 = 0.f;
    #pragma unroll
    for (int j=0;j<D/64;j++){ float dd = v[j]-mu; s2 += dd*dd; }
    #pragma unroll
    for (int o=32;o>=1;o>>=1) s2 += __shfl_xor(s2,o);
    float inv = rsqrtf(s2/(float)D + 1e-5f);
    float* yr = y + (size_t)row*D;
    #pragma unroll
    for (int j=0;j<D/64;j++){
        int d = lane + j*64;
        yr[d] = (v[j]-mu)*inv*w[d] + b[d];
    }
}

// ---------------- generic f32 GEMM: C = epilogue(A[M,K] @ W[N,K]^T) ----------------
// modes: 0 plain, 1 C = R + A@W^T, 2 gelu(exact), 3 store to OutRaw (bf16 or f32 per flag)
#define GBM 64
#define GBN 64
#define GBK 32
__global__ __launch_bounds__(256) void k_gemm(const float* __restrict__ A, const float* __restrict__ W,
        const float* __restrict__ R, float* __restrict__ C, void* __restrict__ OutRaw,
        const int* __restrict__ flag, int M, int N, int K, int mode)
{
    __shared__ float As[GBK][GBM+4];
    __shared__ float Ws[GBK][GBN+4];
    int tid = threadIdx.x;
    int bm = blockIdx.y * GBM;
    int bn = blockIdx.x * GBN;
    int tx = tid & 15, ty = tid >> 4;
    float acc[4][4] = {};
    for (int k0 = 0; k0 < K; k0 += GBK){
        #pragma unroll
        for (int i = tid; i < GBM*GBK; i += 256){
            int m = i >> 5, kk = i & 31;
            As[kk][m] = A[(size_t)(bm+m)*K + k0 + kk];
        }
        #pragma unroll
        for (int i = tid; i < GBN*GBK; i += 256){
            int n = i >> 5, kk = i & 31;
            int gn = bn + n;
            Ws[kk][n] = (gn < N) ? W[(size_t)gn*K + k0 + kk] : 0.0f;
        }
        __syncthreads();
        #pragma unroll
        for (int kk = 0; kk < GBK; kk++){
            float a0[4], w0[4];
            *(float4*)a0 = *(const float4*)&As[kk][ty*4];
            *(float4*)w0 = *(const float4*)&Ws[kk][tx*4];
            #pragma unroll
            for (int i=0;i<4;i++)
                #pragma unroll
                for (int j=0;j<4;j++) acc[i][j] += a0[i]*w0[j];
        }
        __syncthreads();
    }
    #pragma unroll
    for (int i=0;i<4;i++){
        int m = bm + ty*4 + i;
        #pragma unroll
        for (int j=0;j<4;j++){
            int n = bn + tx*4 + j;
            if (n >= N) continue;
            size_t off = (size_t)m*N + n;
            float v = acc[i][j];
            if (mode == 1) v += R[off];
            else if (mode == 2) v = 0.5f*v*(1.0f + erff(v*0.70710678118654752f));
            if (mode == 3){
                if (flag[0]) ((bf16*)OutRaw)[off] = __float2bfloat16(v);
                else         ((float*)OutRaw)[off] = v;
            } else C[off] = v;
        }
    }
}

// ---------------- attention: one wave per (b,h,q) ----------------
__global__ __launch_bounds__(64) void k_attn(const float* __restrict__ qkv, float* __restrict__ out,
        const int* __restrict__ counts, int D, int dh, float scale)
{
    int qp = blockIdx.x, h = blockIdx.y, b = blockIdx.z;
    int lane = threadIdx.x;
    __shared__ float sQ[64];
    __shared__ float sS[L_];
    const float* base = qkv + (size_t)b * L_ * 3 * D;
    if (lane < dh) sQ[lane] = base[(size_t)qp*3*D + h*dh + lane];
    __syncthreads();
    int kmax = qp;
    if (counts){ int c = counts[b]-1; if (c < kmax) kmax = c; }
    float lmax = -1e30f;
    for (int k = lane; k <= kmax; k += 64){
        const float* krow = base + (size_t)k*3*D + D + h*dh;
        float s = 0.f;
        for (int d = 0; d < dh; d += 4){
            float4 kv = *(const float4*)(krow + d);
            s += sQ[d]*kv.x + sQ[d+1]*kv.y + sQ[d+2]*kv.z + sQ[d+3]*kv.w;
        }
        s *= scale;
        sS[k] = s;
        lmax = fmaxf(lmax, s);
    }
    #pragma unroll
    for (int o=32;o>=1;o>>=1) lmax = fmaxf(lmax, __shfl_xor(lmax,o));
    float lsum = 0.f;
    for (int k = lane; k <= kmax; k += 64){
        float e = expf(sS[k] - lmax);
        sS[k] = e; lsum += e;
    }
    #pragma unroll
    for (int o=32;o>=1;o>>=1) lsum += __shfl_xor(lsum,o);
    float inv = 1.0f / lsum;
    __syncthreads();
    if (lane < dh){
        const float* vcol = base + 2*D + h*dh + lane;
        float acc = 0.f;
        for (int k = 0; k <= kmax; k++) acc += sS[k] * vcol[(size_t)k*3*D];
        out[((size_t)b*L_ + qp)*D + h*dh + lane] = acc * inv;
    }
}

// ---------------- router: p/b_hard from cosine of adjacent l2-normed q,k ----------------
__global__ __launch_bounds__(64) void k_router(const float* __restrict__ Q, const float* __restrict__ Kr,
        float* __restrict__ p, float* __restrict__ bh)
{
    int idx = blockIdx.x;
    int t = idx & (L_-1);
    int lane = threadIdx.x;
    float pv;
    if (t == 0){ pv = 1.0f; }
    else {
        const float* qr = Q  + (size_t)idx*DENC;
        const float* kr = Kr + (size_t)(idx-1)*DENC;
        float qq=0.f, kk=0.f, qk=0.f;
        #pragma unroll
        for (int j=0;j<2;j++){
            float qv = qr[lane + j*64], kv = kr[lane + j*64];
            qq += qv*qv; kk += kv*kv; qk += qv*kv;
        }
        #pragma unroll
        for (int o=32;o>=1;o>>=1){ qq += __shfl_xor(qq,o); kk += __shfl_xor(kk,o); qk += __shfl_xor(qk,o); }
        float cosv = qk / (fmaxf(sqrtf(qq),1e-12f)*fmaxf(sqrtf(kk),1e-12f));
        pv = 0.5f*(1.0f - cosv);
        pv = fminf(fmaxf(pv, 0.0f), 1.0f);
    }
    if (lane == 0){ p[idx] = pv; bh[idx] = (pv >= 0.5f) ? 1.0f : 0.0f; }
}

// ---------------- sequential per-batch cumsum / dest / counts ----------------
__global__ void k_seq(const float* __restrict__ bh, int* __restrict__ cidx,
                      int* __restrict__ dest, int* __restrict__ counts){
    int b = threadIdx.x;
    if (b >= B_) return;
    int cum = 0;
    for (int t = 0; t < L_; t++){
        int i = b*L_ + t;
        int h = bh[i] > 0.5f;
        cum += h;
        int ci = cum - 1; if (ci < 0) ci = 0;
        cidx[i] = ci;
        dest[i] = h ? (cum-1) : L_;
    }
    counts[b] = cum;
}

__global__ void k_zero(float* p, int n){ int i = blockIdx.x*256+threadIdx.x; if (i < n) p[i] = 0.f; }

__global__ void k_scatter(const float* __restrict__ x, const float* __restrict__ p,
        const int* __restrict__ dest, const float* __restrict__ bh,
        float* __restrict__ comp, float* __restrict__ pcomp)
{
    int i = blockIdx.x;         // over BL
    int d = threadIdx.x;        // 128
    int b = i >> 10;
    if (bh[i] > 0.5f){
        int ds = dest[i];
        comp[((size_t)b*L_ + ds)*DENC + d] = x[(size_t)i*DENC + d];
        if (d == 0) pcomp[b*L_ + ds] = p[i];
    }
}

__global__ __launch_bounds__(256) void k_reduce(const float* __restrict__ p, const float* __restrict__ bh,
                                                float* __restrict__ acc){
    __shared__ float sp[256], sb[256];
    int tid = threadIdx.x;
    float s1=0.f, s2=0.f;
    for (int i = blockIdx.x*256 + tid; i < BL; i += gridDim.x*256){ s1 += p[i]; s2 += bh[i]; }
    sp[tid]=s1; sb[tid]=s2; __syncthreads();
    for (int o=128;o>=1;o>>=1){ if (tid<o){ sp[tid]+=sp[tid+o]; sb[tid]+=sb[tid+o]; } __syncthreads(); }
    if (tid==0){ atomicAdd(&acc[0], sp[0]); atomicAdd(&acc[1], sb[0]); }
}

// ---------------- chunk EMA scan: thread per (b,d) ----------------
__global__ __launch_bounds__(64) void k_ema(const float* __restrict__ z, const float* __restrict__ pcomp,
                                            float* __restrict__ zbar){
    int gid = blockIdx.x*64 + threadIdx.x;   // over B_*DENC = 1024
    int b = gid >> 7, d = gid & 127;
    const float* zb = z    + (size_t)b*L_*DENC + d;
    float*       ob = zbar + (size_t)b*L_*DENC + d;
    float prev = 0.f;
    for (int t = 0; t < L_; t++){
        float pc = pcomp[b*L_ + t];
        pc = fminf(fmaxf(pc, 1e-4f), 1.0f-1e-4f);
        float zv = zb[(size_t)t*DENC];
        float a  = (t==0) ? 0.0f : (1.0f - pc);
        float bv = (t==0) ? zv : pc*zv;
        prev = a*prev + bv;
        ob[(size_t)t*DENC] = prev;
    }
}

__global__ void k_combine(float* __restrict__ x, const float* __restrict__ zbar, const int* __restrict__ cidx){
    int i = blockIdx.x*256 + threadIdx.x;   // BL*DENC
    int row = i >> 7, d = i & 127;
    int b = row >> 10;
    int ci = cidx[row];
    x[i] += zbar[((size_t)b*L_ + ci)*DENC + d];
}

__global__ void k_loss(const float* __restrict__ acc, void* __restrict__ out, const int* __restrict__ flag){
    float G = acc[0] / (float)BL;
    float F = acc[1] / (float)BL;
    float ratio = 1.2f*(5.0f*F*G + (1.0f-F)*(1.0f-G));   // N=6
    if (flag[0]) ((bf16*)out)[(size_t)BL*VOCAB] = __float2bfloat16(ratio);
    else         ((float*)out)[(size_t)BL*VOCAB] = ratio;
}

// =========================================================================
extern "C" void kernel_launch(void* const* d_in, const int* in_sizes, int n_in,
                              void* d_out, int out_size, void* d_ws, size_t ws_size,
                              hipStream_t stream) {
    (void)out_size; (void)ws_size;
    const int* byte_ids = (const int*)d_in[0];

    float* ws = (float*)d_ws;
    size_t off = 0;
    int* FLAG = (int*)ws; off += 16;
    float* W32 = ws + off;

    // dtype detect + convert all float inputs (indices 1..31) to f32 copies
    k_detect<<<1, 64, 0, stream>>>(d_in[1], FLAG);
    const float* w32[32];
    size_t woff = 0;
    for (int i = 1; i < n_in; i++){
        w32[i] = W32 + woff;
        int n = in_sizes[i];
        k_cvt<<<(n + 255)/256, 256, 0, stream>>>(d_in[i], W32 + woff, n, FLAG);
        woff += (size_t)n;
    }
    off += woff;

    const float* embed    = w32[1];
    const float* wq       = w32[2];
    const float* wk       = w32[3];
    const float* proj_up  = w32[4];
    const float* proj_dn  = w32[5];
    const float* norm_w   = w32[6];
    const float* norm_b   = w32[7];
    const float* enc_ln1w = w32[8];
    const float* enc_ln1b = w32[9];
    const float* enc_qkv  = w32[10];
    const float* enc_wo   = w32[11];
    const float* enc_ln2w = w32[12];
    const float* enc_ln2b = w32[13];
    const float* enc_w1   = w32[14];
    const float* enc_w2   = w32[15];
    const float* main_ln1w= w32[16];
    const float* main_ln1b= w32[17];
    const float* main_qkv = w32[18];
    const float* main_wo  = w32[19];
    const float* main_ln2w= w32[20];
    const float* main_ln2b= w32[21];
    const float* main_w1  = w32[22];
    const float* main_w2  = w32[23];
    const float* dec_ln1w = w32[24];
    const float* dec_ln1b = w32[25];
    const float* dec_qkv  = w32[26];
    const float* dec_wo   = w32[27];
    const float* dec_ln2w = w32[28];
    const float* dec_ln2b = w32[29];
    const float* dec_w1   = w32[30];
    const float* dec_w2   = w32[31];

    float* X    = ws + off; off += (size_t)BL*DENC;
    float* LN   = ws + off; off += (size_t)BL*DMAIN;
    float* QKV  = ws + off; off += (size_t)BL*3*DMAIN;
    float* ATT  = ws + off; off += (size_t)BL*DMAIN;
    float* H    = ws + off; off += (size_t)BL*2*DMAIN;
    float* Z    = ws + off; off += (size_t)BL*DMAIN;
    float* COMP = ws + off; off += (size_t)BL*DENC;
    float* P    = ws + off; off += BL;
    float* BH   = ws + off; off += BL;
    float* PCOMP= ws + off; off += BL;
    float* ACC  = ws + off; off += 8;
    int* CIDX   = (int*)(ws + off); off += BL;
    int* DEST   = (int*)(ws + off); off += BL;
    int* COUNTS = (int*)(ws + off); off += 64;
    float* TMP  = H;                          // router-k scratch (H is dead there)
    float* ZDN  = QKV;                        // alias, live only between main stack and decoder
    float* ZBAR = QKV + (size_t)BL*DENC;

    auto gemm = [&](const float* A, const float* W, const float* R, float* C, void* Ob,
                    int N, int K, int mode){
        dim3 g((N+GBN-1)/GBN, BL/GBM);
        k_gemm<<<g, 256, 0, stream>>>(A, W, R, C, Ob, FLAG, BL, N, K, mode);
    };

    auto block128 = [&](float* Xs, const float* l1w, const float* l1b, const float* qkvw, const float* wo,
                        const float* l2w, const float* l2b, const float* w1, const float* w2){
        k_ln<128><<<BL,64,0,stream>>>(Xs, l1w, l1b, LN);
        gemm(LN, qkvw, nullptr, QKV, nullptr, 3*DENC, DENC, 0);
        k_attn<<<dim3(L_,NHEADS,B_),64,0,stream>>>(QKV, ATT, nullptr, DENC, DENC/NHEADS, 0.17677669529663687f);
        gemm(ATT, wo, Xs, Xs, nullptr, DENC, DENC, 1);
        k_ln<128><<<BL,64,0,stream>>>(Xs, l2w, l2b, LN);
        gemm(LN, w1, nullptr, H, nullptr, 2*DENC, DENC, 2);
        gemm(H, w2, Xs, Xs, nullptr, DENC, 2*DENC, 1);
    };
    auto block256 = [&](float* Xs, const float* l1w, const float* l1b, const float* qkvw, const float* wo,
                        const float* l2w, const float* l2b, const float* w1, const float* w2){
        k_ln<256><<<BL,64,0,stream>>>(Xs, l1w, l1b, LN);
        gemm(LN, qkvw, nullptr, QKV, nullptr, 3*DMAIN, DMAIN, 0);
        k_attn<<<dim3(L_,NHEADS,B_),64,0,stream>>>(QKV, ATT, COUNTS, DMAIN, DMAIN/NHEADS, 0.125f);
        gemm(ATT, wo, Xs, Xs, nullptr, DMAIN, DMAIN, 1);
        k_ln<256><<<BL,64,0,stream>>>(Xs, l2w, l2b, LN);
        gemm(LN, w1, nullptr, H, nullptr, 2*DMAIN, DMAIN, 2);
        gemm(H, w2, Xs, Xs, nullptr, DMAIN, 2*DMAIN, 1);
    };

    // ---- embed + encoder ----
    k_embed<<<BL*DENC/256, 256, 0, stream>>>(byte_ids, embed, X);
    for (int i = 0; i < 3; i++)
        block128(X, enc_ln1w + i*DENC, enc_ln1b + i*DENC, enc_qkv + (size_t)i*3*DENC*DENC,
                 enc_wo + (size_t)i*DENC*DENC, enc_ln2w + i*DENC, enc_ln2b + i*DENC,
                 enc_w1 + (size_t)i*2*DENC*DENC, enc_w2 + (size_t)i*2*DENC*DENC);

    // ---- routing ----
    gemm(X, wq, nullptr, ATT, nullptr, DENC, DENC, 0);   // q raw
    gemm(X, wk, nullptr, TMP, nullptr, DENC, DENC, 0);   // k raw
    k_router<<<BL, 64, 0, stream>>>(ATT, TMP, P, BH);
    k_seq<<<1, 64, 0, stream>>>(BH, CIDX, DEST, COUNTS);
    k_zero<<<(BL*DENC+255)/256, 256, 0, stream>>>(COMP, BL*DENC);
    k_zero<<<(BL+255)/256, 256, 0, stream>>>(PCOMP, BL);
    k_zero<<<1, 256, 0, stream>>>(ACC, 8);
    k_scatter<<<BL, 128, 0, stream>>>(X, P, DEST, BH, COMP, PCOMP);
    k_reduce<<<8, 256, 0, stream>>>(P, BH, ACC);

    // ---- main stack on compressed ----
    gemm(COMP, proj_up, nullptr, Z, nullptr, DMAIN, DENC, 0);
    for (int i = 0; i < 6; i++)
        block256(Z, main_ln1w + i*DMAIN, main_ln1b + i*DMAIN, main_qkv + (size_t)i*3*DMAIN*DMAIN,
                 main_wo + (size_t)i*DMAIN*DMAIN, main_ln2w + i*DMAIN, main_ln2b + i*DMAIN,
                 main_w1 + (size_t)i*2*DMAIN*DMAIN, main_w2 + (size_t)i*2*DMAIN*DMAIN);
    gemm(Z, proj_dn, nullptr, ZDN, nullptr, DENC, DMAIN, 0);

    // ---- EMA + dechunk combine ----
    k_ema<<<B_*DENC/64, 64, 0, stream>>>(ZDN, PCOMP, ZBAR);
    k_combine<<<BL*DENC/256, 256, 0, stream>>>(X, ZBAR, CIDX);

    // ---- decoder ----
    for (int i = 0; i < 3; i++)
        block128(X, dec_ln1w + i*DENC, dec_ln1b + i*DENC, dec_qkv + (size_t)i*3*DENC*DENC,
                 dec_wo + (size_t)i*DENC*DENC, dec_ln2w + i*DENC, dec_ln2b + i*DENC,
                 dec_w1 + (size_t)i*2*DENC*DENC, dec_w2 + (size_t)i*2*DENC*DENC);

    // ---- final LN + tied head + loss ----
    k_ln<128><<<BL,64,0,stream>>>(X, norm_w, norm_b, LN);
    gemm(LN, embed, nullptr, nullptr, d_out, VOCAB, DENC, 3);
    k_loss<<<1,1,0,stream>>>(ACC, d_out, FLAG);
}

// Round 3
// 3717.620 us; speedup vs baseline: 1.5090x; 1.5090x over previous
//
#include <hip/hip_runtime.h>
#include <hip/hip_bf16.h>

#define B_ 8
#define L_ 1024
#define BL (B_*L_)
#define DENC 128
#define DMAIN 256
#define VOCAB 260
#define NHEADS 4

typedef __hip_bfloat16 bf16;

// ---------------- dtype detector: flag=1 if inputs are bf16, 0 if f32 ----------------
__global__ __launch_bounds__(64) void k_detect(const void* __restrict__ emb, int* __restrict__ flag){
    int lane = threadIdx.x;
    const unsigned short* u = (const unsigned short*)emb;
    int bad = 0;
    #pragma unroll
    for (int j = 0; j < 4; j++){
        unsigned short h = u[lane + 64*j];
        bf16 t = *(const bf16*)&h;
        float v = __bfloat162float(t);
        if (!(fabsf(v) < 1e4f)) bad++;
    }
    #pragma unroll
    for (int o = 32; o >= 1; o >>= 1) bad += __shfl_xor(bad, o);
    if (lane == 0) flag[0] = (bad == 0) ? 1 : 0;
}

// ---------------- fused convert of all 31 float inputs ----------------
struct CvtArgs {
    const void* src[31];
    unsigned offs[32];   // offs[s] = start of segment s in dst; offs[31] = total
};
__global__ void k_cvt_all(CvtArgs a, float* __restrict__ dst, int total, const int* __restrict__ flag){
    int isbf = flag[0];
    for (int i = blockIdx.x*256 + threadIdx.x; i < total; i += gridDim.x*256){
        int lo = 0, hi = 30;
        while (lo < hi){ int mid = (lo+hi+1)>>1; if (a.offs[mid] <= (unsigned)i) lo = mid; else hi = mid-1; }
        int j = i - (int)a.offs[lo];
        dst[i] = isbf ? __bfloat162float(((const bf16*)a.src[lo])[j])
                      : ((const float*)a.src[lo])[j];
    }
}

// ---------------- embed gather ----------------
__global__ void k_embed(const int* __restrict__ ids, const float* __restrict__ emb, float* __restrict__ x){
    int i = blockIdx.x*256 + threadIdx.x;      // over BL*DENC
    int row = i >> 7, d = i & 127;
    x[i] = emb[ids[row]*DENC + d];
}

// ---------------- layernorm (one wave per row) ----------------
template<int D>
__global__ __launch_bounds__(64) void k_ln(const float* __restrict__ x, const float* __restrict__ w,
                                           const float* __restrict__ b, float* __restrict__ y){
    int row = blockIdx.x;
    int lane = threadIdx.x;
    const float* xr = x + (size_t)row*D;
    float v[D/64];
    float s = 0.f;
    #pragma unroll
    for (int j=0;j<D/64;j++){ v[j] = xr[lane + j*64]; s += v[j]; }
    #pragma unroll
    for (int o=32;o>=1;o>>=1) s += __shfl_xor(s,o);
    float mu = s / (float)D;
    float s2 = 0.f;
    #pragma unroll
    for (int j=0;j<D/64;j++){ float dd = v[j]-mu; s2 += dd*dd; }
    #pragma unroll
    for (int o=32;o>=1;o>>=1) s2 += __shfl_xor(s2,o);
    float inv = rsqrtf(s2/(float)D + 1e-5f);
    float* yr = y + (size_t)row*D;
    #pragma unroll
    for (int j=0;j<D/64;j++){
        int d = lane + j*64;
        yr[d] = (v[j]-mu)*inv*w[d] + b[d];
    }
}

// ---------------- generic f32 GEMM: C = epilogue(A[M,K] @ W[N,K]^T) ----------------
// modes: 0 plain, 1 C = R + A@W^T, 2 gelu(exact), 3 store to OutRaw (bf16/f32 per flag),
//        4 split-head QKV store: n -> (which,h,d), row m -> (b,t); dst[which][b][h][t][d]
#define GBM 64
#define GBN 64
#define GBK 32
__global__ __launch_bounds__(256) void k_gemm(const float* __restrict__ A, const float* __restrict__ W,
        const float* __restrict__ R, float* __restrict__ C, void* __restrict__ OutRaw,
        const int* __restrict__ flag, int M, int N, int K, int mode,
        float* __restrict__ Qd, float* __restrict__ Kd, float* __restrict__ Vd,
        int dShift, int dhShift)
{
    __shared__ float As[GBK][GBM+4];
    __shared__ float Ws[GBK][GBN+4];
    int tid = threadIdx.x;
    int bm = blockIdx.y * GBM;
    int bn = blockIdx.x * GBN;
    int tx = tid & 15, ty = tid >> 4;
    float acc[4][4] = {};
    for (int k0 = 0; k0 < K; k0 += GBK){
        #pragma unroll
        for (int i = tid; i < GBM*GBK; i += 256){
            int m = i >> 5, kk = i & 31;
            As[kk][m] = A[(size_t)(bm+m)*K + k0 + kk];
        }
        #pragma unroll
        for (int i = tid; i < GBN*GBK; i += 256){
            int n = i >> 5, kk = i & 31;
            int gn = bn + n;
            Ws[kk][n] = (gn < N) ? W[(size_t)gn*K + k0 + kk] : 0.0f;
        }
        __syncthreads();
        #pragma unroll
        for (int kk = 0; kk < GBK; kk++){
            float a0[4], w0[4];
            *(float4*)a0 = *(const float4*)&As[kk][ty*4];
            *(float4*)w0 = *(const float4*)&Ws[kk][tx*4];
            #pragma unroll
            for (int i=0;i<4;i++)
                #pragma unroll
                for (int j=0;j<4;j++) acc[i][j] += a0[i]*w0[j];
        }
        __syncthreads();
    }
    #pragma unroll
    for (int i=0;i<4;i++){
        int m = bm + ty*4 + i;
        #pragma unroll
        for (int j=0;j<4;j++){
            int n = bn + tx*4 + j;
            if (n >= N) continue;
            float v = acc[i][j];
            if (mode == 4){
                int which = n >> dShift;
                int rem = n & ((1<<dShift)-1);
                int hh = rem >> dhShift;
                int dd = rem & ((1<<dhShift)-1);
                int bb = m >> 10, tt = m & 1023;
                int Hn = 1 << (dShift - dhShift);
                float* dst = (which==0) ? Qd : ((which==1) ? Kd : Vd);
                dst[((((size_t)bb*Hn + hh)*L_ + tt) << dhShift) + dd] = v;
                continue;
            }
            size_t off = (size_t)m*N + n;
            if (mode == 1) v += R[off];
            else if (mode == 2) v = 0.5f*v*(1.0f + erff(v*0.70710678118654752f));
            if (mode == 3){
                if (flag[0]) ((bf16*)OutRaw)[off] = __float2bfloat16(v);
                else         ((float*)OutRaw)[off] = v;
            } else C[off] = v;
        }
    }
}

// ---------------- flash attention: block per (b,h, 64-query tile) ----------------
template<int DH>
__global__ __launch_bounds__(256) void k_flash(const float* __restrict__ Qh, const float* __restrict__ Kh,
        const float* __restrict__ Vh, float* __restrict__ out, const int* __restrict__ counts,
        float scale)
{
    constexpr int BQ = 64, BK = 64;
    constexpr int QS = BQ + 1;           // padded stride
    __shared__ float sQt[DH*QS];         // Q transposed [d][q]
    __shared__ float sKP[BK*QS];         // K transposed [d][k] during QK; P transposed [k][q] during PV
    __shared__ float sV [BK*DH];         // V row-major [k][d]

    int x = blockIdx.x;                  // b*NHEADS + h
    int b = x >> 2;
    int yy = blockIdx.y;
    int qt = (yy < 8) ? yy : 23 - yy;    // pair low/high triangle rows across co-resident blocks
    int q0 = qt * BQ;

    int tid = threadIdx.x;
    int tx = tid & 15, ty = tid >> 4;

    const float* Qb = Qh + ((size_t)x*L_)*DH;
    const float* Kb = Kh + ((size_t)x*L_)*DH;
    const float* Vb = Vh + ((size_t)x*L_)*DH;

    int kcap = counts ? counts[b] : L_;
    int klen = min(kcap, q0 + BQ);

    // stage Q transposed (coalesced global float4, 2-way-free LDS writes)
    {
        const float4* src = (const float4*)(Qb + (size_t)q0*DH);
        for (int i = tid; i < BQ*DH/4; i += 256){
            float4 v = src[i];
            int t = (4*i) / DH, d = (4*i) % DH;
            sQt[(d+0)*QS + t] = v.x;
            sQt[(d+1)*QS + t] = v.y;
            sQt[(d+2)*QS + t] = v.z;
            sQt[(d+3)*QS + t] = v.w;
        }
    }

    float m[4], l[4], o[4][4];
    #pragma unroll
    for (int i=0;i<4;i++){ m[i] = -1e30f; l[i] = 0.f;
        #pragma unroll
        for (int j=0;j<4;j++) o[i][j] = 0.f; }

    for (int k0 = 0; k0 < klen; k0 += BK){
        __syncthreads();                 // prev PV done (and Qt ready on first iter)
        {
            const float4* ks = (const float4*)(Kb + (size_t)k0*DH);
            const float4* vs = (const float4*)(Vb + (size_t)k0*DH);
            for (int i = tid; i < BK*DH/4; i += 256){
                float4 kv = ks[i];
                int t = (4*i) / DH, d = (4*i) % DH;
                sKP[(d+0)*QS + t] = kv.x;
                sKP[(d+1)*QS + t] = kv.y;
                sKP[(d+2)*QS + t] = kv.z;
                sKP[(d+3)*QS + t] = kv.w;
                ((float4*)sV)[i] = vs[i];
            }
        }
        __syncthreads();

        // S[4q][4k] microtile
        float s[4][4] = {};
        #pragma unroll 4
        for (int d = 0; d < DH; d++){
            float4 qv = *(const float4*)&sQt[d*QS + ty*4];
            float4 kv = *(const float4*)&sKP[d*QS + tx*4];
            s[0][0] += qv.x*kv.x; s[0][1] += qv.x*kv.y; s[0][2] += qv.x*kv.z; s[0][3] += qv.x*kv.w;
            s[1][0] += qv.y*kv.x; s[1][1] += qv.y*kv.y; s[1][2] += qv.y*kv.z; s[1][3] += qv.y*kv.w;
            s[2][0] += qv.z*kv.x; s[2][1] += qv.z*kv.y; s[2][2] += qv.z*kv.z; s[2][3] += qv.z*kv.w;
            s[3][0] += qv.w*kv.x; s[3][1] += qv.w*kv.y; s[3][2] += qv.w*kv.z; s[3][3] += qv.w*kv.w;
        }
        bool needmask = (k0 >= q0) || (k0 + BK > kcap);
        #pragma unroll
        for (int i=0;i<4;i++){
            int q = q0 + ty*4 + i;
            #pragma unroll
            for (int j=0;j<4;j++){
                float v = s[i][j]*scale;
                if (needmask){
                    int k = k0 + tx*4 + j;
                    if (k > q || k >= kcap) v = -1e30f;
                }
                s[i][j] = v;
            }
        }
        __syncthreads();                 // done reading Kt; sKP becomes Pt

        #pragma unroll
        for (int i=0;i<4;i++){
            float rm = fmaxf(fmaxf(s[i][0],s[i][1]), fmaxf(s[i][2],s[i][3]));
            rm = fmaxf(rm, __shfl_xor(rm, 1));
            rm = fmaxf(rm, __shfl_xor(rm, 2));
            rm = fmaxf(rm, __shfl_xor(rm, 4));
            rm = fmaxf(rm, __shfl_xor(rm, 8));
            float mn = fmaxf(m[i], rm);
            float al = __expf(m[i] - mn);
            float p0 = __expf(s[i][0]-mn), p1 = __expf(s[i][1]-mn);
            float p2 = __expf(s[i][2]-mn), p3 = __expf(s[i][3]-mn);
            float rs = p0+p1+p2+p3;
            rs += __shfl_xor(rs, 1);
            rs += __shfl_xor(rs, 2);
            rs += __shfl_xor(rs, 4);
            rs += __shfl_xor(rs, 8);
            l[i] = l[i]*al + rs;
            m[i] = mn;
            o[i][0]*=al; o[i][1]*=al; o[i][2]*=al; o[i][3]*=al;
            sKP[(tx*4+0)*QS + ty*4 + i] = p0;
            sKP[(tx*4+1)*QS + ty*4 + i] = p1;
            sKP[(tx*4+2)*QS + ty*4 + i] = p2;
            sKP[(tx*4+3)*QS + ty*4 + i] = p3;
        }
        __syncthreads();

        if (tx*4 < DH){
            #pragma unroll 4
            for (int k = 0; k < BK; k++){
                float4 pv = *(const float4*)&sKP[k*QS + ty*4];
                float4 vv = *(const float4*)&sV[k*DH + tx*4];
                o[0][0] += pv.x*vv.x; o[0][1] += pv.x*vv.y; o[0][2] += pv.x*vv.z; o[0][3] += pv.x*vv.w;
                o[1][0] += pv.y*vv.x; o[1][1] += pv.y*vv.y; o[1][2] += pv.y*vv.z; o[1][3] += pv.y*vv.w;
                o[2][0] += pv.z*vv.x; o[2][1] += pv.z*vv.y; o[2][2] += pv.z*vv.z; o[2][3] += pv.z*vv.w;
                o[3][0] += pv.w*vv.x; o[3][1] += pv.w*vv.y; o[3][2] += pv.w*vv.z; o[3][3] += pv.w*vv.w;
            }
        }
    }

    if (tx*4 < DH){
        int h = x & 3;
        #pragma unroll
        for (int i=0;i<4;i++){
            float inv = 1.0f / l[i];
            int q = q0 + ty*4 + i;
            float4 r = make_float4(o[i][0]*inv, o[i][1]*inv, o[i][2]*inv, o[i][3]*inv);
            *(float4*)&out[((size_t)b*L_ + q)*(4*DH) + h*DH + tx*4] = r;
        }
    }
}

// ---------------- router ----------------
__global__ __launch_bounds__(64) void k_router(const float* __restrict__ Q, const float* __restrict__ Kr,
        float* __restrict__ p, float* __restrict__ bh)
{
    int idx = blockIdx.x;
    int t = idx & (L_-1);
    int lane = threadIdx.x;
    float pv;
    if (t == 0){ pv = 1.0f; }
    else {
        const float* qr = Q  + (size_t)idx*DENC;
        const float* kr = Kr + (size_t)(idx-1)*DENC;
        float qq=0.f, kk=0.f, qk=0.f;
        #pragma unroll
        for (int j=0;j<2;j++){
            float qv = qr[lane + j*64], kv = kr[lane + j*64];
            qq += qv*qv; kk += kv*kv; qk += qv*kv;
        }
        #pragma unroll
        for (int o=32;o>=1;o>>=1){ qq += __shfl_xor(qq,o); kk += __shfl_xor(kk,o); qk += __shfl_xor(qk,o); }
        float cosv = qk / (fmaxf(sqrtf(qq),1e-12f)*fmaxf(sqrtf(kk),1e-12f));
        pv = 0.5f*(1.0f - cosv);
        pv = fminf(fmaxf(pv, 0.0f), 1.0f);
    }
    if (lane == 0){ p[idx] = pv; bh[idx] = (pv >= 0.5f) ? 1.0f : 0.0f; }
}

// ---------------- sequential per-batch cumsum / dest / counts ----------------
__global__ void k_seq(const float* __restrict__ bh, int* __restrict__ cidx,
                      int* __restrict__ dest, int* __restrict__ counts){
    int b = threadIdx.x;
    if (b >= B_) return;
    int cum = 0;
    for (int t = 0; t < L_; t++){
        int i = b*L_ + t;
        int h = bh[i] > 0.5f;
        cum += h;
        int ci = cum - 1; if (ci < 0) ci = 0;
        cidx[i] = ci;
        dest[i] = h ? (cum-1) : L_;
    }
    counts[b] = cum;
}

__global__ void k_zero(float* p, int n){ int i = blockIdx.x*256+threadIdx.x; if (i < n) p[i] = 0.f; }

__global__ void k_scatter(const float* __restrict__ x, const float* __restrict__ p,
        const int* __restrict__ dest, const float* __restrict__ bh,
        float* __restrict__ comp, float* __restrict__ pcomp)
{
    int i = blockIdx.x;
    int d = threadIdx.x;
    int b = i >> 10;
    if (bh[i] > 0.5f){
        int ds = dest[i];
        comp[((size_t)b*L_ + ds)*DENC + d] = x[(size_t)i*DENC + d];
        if (d == 0) pcomp[b*L_ + ds] = p[i];
    }
}

__global__ __launch_bounds__(256) void k_reduce(const float* __restrict__ p, const float* __restrict__ bh,
                                                float* __restrict__ acc){
    __shared__ float sp[256], sb[256];
    int tid = threadIdx.x;
    float s1=0.f, s2=0.f;
    for (int i = blockIdx.x*256 + tid; i < BL; i += gridDim.x*256){ s1 += p[i]; s2 += bh[i]; }
    sp[tid]=s1; sb[tid]=s2; __syncthreads();
    for (int o=128;o>=1;o>>=1){ if (tid<o){ sp[tid]+=sp[tid+o]; sb[tid]+=sb[tid+o]; } __syncthreads(); }
    if (tid==0){ atomicAdd(&acc[0], sp[0]); atomicAdd(&acc[1], sb[0]); }
}

// ---------------- chunk EMA scan ----------------
__global__ __launch_bounds__(64) void k_ema(const float* __restrict__ z, const float* __restrict__ pcomp,
                                            float* __restrict__ zbar){
    int gid = blockIdx.x*64 + threadIdx.x;
    int b = gid >> 7, d = gid & 127;
    const float* zb = z    + (size_t)b*L_*DENC + d;
    float*       ob = zbar + (size_t)b*L_*DENC + d;
    float prev = 0.f;
    for (int t = 0; t < L_; t++){
        float pc = pcomp[b*L_ + t];
        pc = fminf(fmaxf(pc, 1e-4f), 1.0f-1e-4f);
        float zv = zb[(size_t)t*DENC];
        float a  = (t==0) ? 0.0f : (1.0f - pc);
        float bv = (t==0) ? zv : pc*zv;
        prev = a*prev + bv;
        ob[(size_t)t*DENC] = prev;
    }
}

__global__ void k_combine(float* __restrict__ x, const float* __restrict__ zbar, const int* __restrict__ cidx){
    int i = blockIdx.x*256 + threadIdx.x;
    int row = i >> 7, d = i & 127;
    int b = row >> 10;
    int ci = cidx[row];
    x[i] += zbar[((size_t)b*L_ + ci)*DENC + d];
}

__global__ void k_loss(const float* __restrict__ acc, void* __restrict__ out, const int* __restrict__ flag){
    float G = acc[0] / (float)BL;
    float F = acc[1] / (float)BL;
    float ratio = 1.2f*(5.0f*F*G + (1.0f-F)*(1.0f-G));
    if (flag[0]) ((bf16*)out)[(size_t)BL*VOCAB] = __float2bfloat16(ratio);
    else         ((float*)out)[(size_t)BL*VOCAB] = ratio;
}

// =========================================================================
extern "C" void kernel_launch(void* const* d_in, const int* in_sizes, int n_in,
                              void* d_out, int out_size, void* d_ws, size_t ws_size,
                              hipStream_t stream) {
    (void)out_size; (void)ws_size;
    const int* byte_ids = (const int*)d_in[0];

    float* ws = (float*)d_ws;
    size_t off = 0;
    int* FLAG = (int*)ws; off += 16;
    float* W32 = ws + off;

    k_detect<<<1, 64, 0, stream>>>(d_in[1], FLAG);

    CvtArgs ca;
    const float* w32[32];
    unsigned woff = 0;
    for (int i = 1; i < n_in && i < 32; i++){
        w32[i] = W32 + woff;
        ca.src[i-1] = d_in[i];
        ca.offs[i-1] = woff;
        woff += (unsigned)in_sizes[i];
    }
    ca.offs[31] = woff;
    k_cvt_all<<<2048, 256, 0, stream>>>(ca, W32, (int)woff, FLAG);
    off += woff;

    const float* embed    = w32[1];
    const float* wq       = w32[2];
    const float* wk       = w32[3];
    const float* proj_up  = w32[4];
    const float* proj_dn  = w32[5];
    const float* norm_w   = w32[6];
    const float* norm_b   = w32[7];
    const float* enc_ln1w = w32[8];
    const float* enc_ln1b = w32[9];
    const float* enc_qkv  = w32[10];
    const float* enc_wo   = w32[11];
    const float* enc_ln2w = w32[12];
    const float* enc_ln2b = w32[13];
    const float* enc_w1   = w32[14];
    const float* enc_w2   = w32[15];
    const float* main_ln1w= w32[16];
    const float* main_ln1b= w32[17];
    const float* main_qkv = w32[18];
    const float* main_wo  = w32[19];
    const float* main_ln2w= w32[20];
    const float* main_ln2b= w32[21];
    const float* main_w1  = w32[22];
    const float* main_w2  = w32[23];
    const float* dec_ln1w = w32[24];
    const float* dec_ln1b = w32[25];
    const float* dec_qkv  = w32[26];
    const float* dec_wo   = w32[27];
    const float* dec_ln2w = w32[28];
    const float* dec_ln2b = w32[29];
    const float* dec_w1   = w32[30];
    const float* dec_w2   = w32[31];

    float* X    = ws + off; off += (size_t)BL*DENC;
    float* LN   = ws + off; off += (size_t)BL*DMAIN;
    float* QKV  = ws + off; off += (size_t)BL*3*DMAIN;
    float* ATT  = ws + off; off += (size_t)BL*DMAIN;
    float* H    = ws + off; off += (size_t)BL*2*DMAIN;
    float* Z    = ws + off; off += (size_t)BL*DMAIN;
    float* COMP = ws + off; off += (size_t)BL*DENC;
    float* P    = ws + off; off += BL;
    float* BH   = ws + off; off += BL;
    float* PCOMP= ws + off; off += BL;
    float* ACC  = ws + off; off += 8;
    int* CIDX   = (int*)(ws + off); off += BL;
    int* DEST   = (int*)(ws + off); off += BL;
    int* COUNTS = (int*)(ws + off); off += 64;
    float* TMP  = H;
    float* ZDN  = QKV;
    float* ZBAR = QKV + (size_t)BL*DENC;

    auto gemm = [&](const float* A, const float* W, const float* R, float* C, void* Ob,
                    int N, int K, int mode){
        dim3 g((N+GBN-1)/GBN, BL/GBM);
        k_gemm<<<g, 256, 0, stream>>>(A, W, R, C, Ob, FLAG, BL, N, K, mode,
                                      nullptr, nullptr, nullptr, 0, 0);
    };
    auto gemm_qkv = [&](const float* A, const float* W, int D, int dh){
        int N = 3*D;
        dim3 g(N/GBN, BL/GBM);
        int dS = (D == 128) ? 7 : 8;
        int dhS = (dh == 32) ? 5 : 6;
        float* Qh = QKV;
        float* Kh = QKV + (size_t)BL*D;
        float* Vh = QKV + (size_t)2*BL*D;
        k_gemm<<<g, 256, 0, stream>>>(A, W, nullptr, nullptr, nullptr, FLAG, BL, N, D, 4,
                                      Qh, Kh, Vh, dS, dhS);
    };

    auto block128 = [&](float* Xs, const float* l1w, const float* l1b, const float* qkvw, const float* wo,
                        const float* l2w, const float* l2b, const float* w1, const float* w2){
        k_ln<128><<<BL,64,0,stream>>>(Xs, l1w, l1b, LN);
        gemm_qkv(LN, qkvw, DENC, 32);
        k_flash<32><<<dim3(B_*NHEADS,16),256,0,stream>>>(QKV, QKV+(size_t)BL*DENC, QKV+(size_t)2*BL*DENC,
                                                         ATT, nullptr, 0.17677669529663687f);
        gemm(ATT, wo, Xs, Xs, nullptr, DENC, DENC, 1);
        k_ln<128><<<BL,64,0,stream>>>(Xs, l2w, l2b, LN);
        gemm(LN, w1, nullptr, H, nullptr, 2*DENC, DENC, 2);
        gemm(H, w2, Xs, Xs, nullptr, DENC, 2*DENC, 1);
    };
    auto block256 = [&](float* Xs, const float* l1w, const float* l1b, const float* qkvw, const float* wo,
                        const float* l2w, const float* l2b, const float* w1, const float* w2){
        k_ln<256><<<BL,64,0,stream>>>(Xs, l1w, l1b, LN);
        gemm_qkv(LN, qkvw, DMAIN, 64);
        k_flash<64><<<dim3(B_*NHEADS,16),256,0,stream>>>(QKV, QKV+(size_t)BL*DMAIN, QKV+(size_t)2*BL*DMAIN,
                                                         ATT, COUNTS, 0.125f);
        gemm(ATT, wo, Xs, Xs, nullptr, DMAIN, DMAIN, 1);
        k_ln<256><<<BL,64,0,stream>>>(Xs, l2w, l2b, LN);
        gemm(LN, w1, nullptr, H, nullptr, 2*DMAIN, DMAIN, 2);
        gemm(H, w2, Xs, Xs, nullptr, DMAIN, 2*DMAIN, 1);
    };

    // ---- embed + encoder ----
    k_embed<<<BL*DENC/256, 256, 0, stream>>>(byte_ids, embed, X);
    for (int i = 0; i < 3; i++)
        block128(X, enc_ln1w + i*DENC, enc_ln1b + i*DENC, enc_qkv + (size_t)i*3*DENC*DENC,
                 enc_wo + (size_t)i*DENC*DENC, enc_ln2w + i*DENC, enc_ln2b + i*DENC,
                 enc_w1 + (size_t)i*2*DENC*DENC, enc_w2 + (size_t)i*2*DENC*DENC);

    // ---- routing ----
    gemm(X, wq, nullptr, ATT, nullptr, DENC, DENC, 0);
    gemm(X, wk, nullptr, TMP, nullptr, DENC, DENC, 0);
    k_router<<<BL, 64, 0, stream>>>(ATT, TMP, P, BH);
    k_seq<<<1, 64, 0, stream>>>(BH, CIDX, DEST, COUNTS);
    k_zero<<<(BL*DENC+255)/256, 256, 0, stream>>>(COMP, BL*DENC);
    k_zero<<<(BL+255)/256, 256, 0, stream>>>(PCOMP, BL);
    k_zero<<<1, 256, 0, stream>>>(ACC, 8);
    k_scatter<<<BL, 128, 0, stream>>>(X, P, DEST, BH, COMP, PCOMP);
    k_reduce<<<8, 256, 0, stream>>>(P, BH, ACC);

    // ---- main stack on compressed ----
    gemm(COMP, proj_up, nullptr, Z, nullptr, DMAIN, DENC, 0);
    for (int i = 0; i < 6; i++)
        block256(Z, main_ln1w + i*DMAIN, main_ln1b + i*DMAIN, main_qkv + (size_t)i*3*DMAIN*DMAIN,
                 main_wo + (size_t)i*DMAIN*DMAIN, main_ln2w + i*DMAIN, main_ln2b + i*DMAIN,
                 main_w1 + (size_t)i*2*DMAIN*DMAIN, main_w2 + (size_t)i*2*DMAIN*DMAIN);
    gemm(Z, proj_dn, nullptr, ZDN, nullptr, DENC, DMAIN, 0);

    // ---- EMA + dechunk combine ----
    k_ema<<<B_*DENC/64, 64, 0, stream>>>(ZDN, PCOMP, ZBAR);
    k_combine<<<BL*DENC/256, 256, 0, stream>>>(X, ZBAR, CIDX);

    // ---- decoder ----
    for (int i = 0; i < 3; i++)
        block128(X, dec_ln1w + i*DENC, dec_ln1b + i*DENC, dec_qkv + (size_t)i*3*DENC*DENC,
                 dec_wo + (size_t)i*DENC*DENC, dec_ln2w + i*DENC, dec_ln2b + i*DENC,
                 dec_w1 + (size_t)i*2*DENC*DENC, dec_w2 + (size_t)i*2*DENC*DENC);

    // ---- final LN + tied head + loss ----
    k_ln<128><<<BL,64,0,stream>>>(X, norm_w, norm_b, LN);
    gemm(LN, embed, nullptr, nullptr, d_out, VOCAB, DENC, 3);
    k_loss<<<1,1,0,stream>>>(ACC, d_out, FLAG);
}

// Round 4
// 2553.450 us; speedup vs baseline: 2.1969x; 1.4559x over previous
//
#include <hip/hip_runtime.h>
#include <hip/hip_bf16.h>

#define B_ 8
#define L_ 1024
#define BL (B_*L_)
#define DENC 128
#define DMAIN 256
#define VOCAB 260
#define NHEADS 4

typedef __hip_bfloat16 bf16;
typedef _Float16 f16;
typedef f16 half8 __attribute__((ext_vector_type(8)));
typedef float f32x4 __attribute__((ext_vector_type(4)));

// ---------------- dtype detector: flag=1 if inputs are bf16, 0 if f32 ----------------
__global__ __launch_bounds__(64) void k_detect(const void* __restrict__ emb, int* __restrict__ flag){
    int lane = threadIdx.x;
    const unsigned short* u = (const unsigned short*)emb;
    int bad = 0;
    #pragma unroll
    for (int j = 0; j < 4; j++){
        unsigned short h = u[lane + 64*j];
        bf16 t = *(const bf16*)&h;
        float v = __bfloat162float(t);
        if (!(fabsf(v) < 1e4f)) bad++;
    }
    #pragma unroll
    for (int o = 32; o >= 1; o >>= 1) bad += __shfl_xor(bad, o);
    if (lane == 0) flag[0] = (bad == 0) ? 1 : 0;
}

// ---------------- fused convert of all 31 float inputs ----------------
struct CvtArgs {
    const void* src[31];
    unsigned offs[32];
};
__global__ void k_cvt_all(CvtArgs a, float* __restrict__ dst, int total, const int* __restrict__ flag){
    int isbf = flag[0];
    for (int i = blockIdx.x*256 + threadIdx.x; i < total; i += gridDim.x*256){
        int lo = 0, hi = 30;
        while (lo < hi){ int mid = (lo+hi+1)>>1; if (a.offs[mid] <= (unsigned)i) lo = mid; else hi = mid-1; }
        int j = i - (int)a.offs[lo];
        dst[i] = isbf ? __bfloat162float(((const bf16*)a.src[lo])[j])
                      : ((const float*)a.src[lo])[j];
    }
}

// ---------------- embed gather ----------------
__global__ void k_embed(const int* __restrict__ ids, const float* __restrict__ emb, float* __restrict__ x){
    int i = blockIdx.x*256 + threadIdx.x;
    int row = i >> 7, d = i & 127;
    x[i] = emb[ids[row]*DENC + d];
}

// ---------------- layernorm (one wave per row) ----------------
template<int D>
__global__ __launch_bounds__(64) void k_ln(const float* __restrict__ x, const float* __restrict__ w,
                                           const float* __restrict__ b, float* __restrict__ y){
    int row = blockIdx.x;
    int lane = threadIdx.x;
    const float* xr = x + (size_t)row*D;
    float v[D/64];
    float s = 0.f;
    #pragma unroll
    for (int j=0;j<D/64;j++){ v[j] = xr[lane + j*64]; s += v[j]; }
    #pragma unroll
    for (int o=32;o>=1;o>>=1) s += __shfl_xor(s,o);
    float mu = s / (float)D;
    float s2 = 0.f;
    #pragma unroll
    for (int j=0;j<D/64;j++){ float dd = v[j]-mu; s2 += dd*dd; }
    #pragma unroll
    for (int o=32;o>=1;o>>=1) s2 += __shfl_xor(s2,o);
    float inv = rsqrtf(s2/(float)D + 1e-5f);
    float* yr = y + (size_t)row*D;
    #pragma unroll
    for (int j=0;j<D/64;j++){
        int d = lane + j*64;
        yr[d] = (v[j]-mu)*inv*w[d] + b[d];
    }
}

// ---------------- f32 vector GEMM (encoder + router only) ----------------
// modes: 0 plain, 1 C = R + A@W^T, 2 gelu, 3 out-store, 4 split-head QKV
#define GBM 64
#define GBN 64
#define GBK 32
__global__ __launch_bounds__(256) void k_gemm(const float* __restrict__ A, const float* __restrict__ W,
        const float* __restrict__ R, float* __restrict__ C, void* __restrict__ OutRaw,
        const int* __restrict__ flag, int M, int N, int K, int mode,
        float* __restrict__ Qd, float* __restrict__ Kd, float* __restrict__ Vd,
        int dShift, int dhShift)
{
    __shared__ float As[GBK][GBM+4];
    __shared__ float Ws[GBK][GBN+4];
    int tid = threadIdx.x;
    int bm = blockIdx.y * GBM;
    int bn = blockIdx.x * GBN;
    int tx = tid & 15, ty = tid >> 4;
    float acc[4][4] = {};
    for (int k0 = 0; k0 < K; k0 += GBK){
        #pragma unroll
        for (int i = tid; i < GBM*GBK; i += 256){
            int m = i >> 5, kk = i & 31;
            As[kk][m] = A[(size_t)(bm+m)*K + k0 + kk];
        }
        #pragma unroll
        for (int i = tid; i < GBN*GBK; i += 256){
            int n = i >> 5, kk = i & 31;
            int gn = bn + n;
            Ws[kk][n] = (gn < N) ? W[(size_t)gn*K + k0 + kk] : 0.0f;
        }
        __syncthreads();
        #pragma unroll
        for (int kk = 0; kk < GBK; kk++){
            float a0[4], w0[4];
            *(float4*)a0 = *(const float4*)&As[kk][ty*4];
            *(float4*)w0 = *(const float4*)&Ws[kk][tx*4];
            #pragma unroll
            for (int i=0;i<4;i++)
                #pragma unroll
                for (int j=0;j<4;j++) acc[i][j] += a0[i]*w0[j];
        }
        __syncthreads();
    }
    #pragma unroll
    for (int i=0;i<4;i++){
        int m = bm + ty*4 + i;
        #pragma unroll
        for (int j=0;j<4;j++){
            int n = bn + tx*4 + j;
            if (n >= N) continue;
            float v = acc[i][j];
            if (mode == 4){
                int which = n >> dShift;
                int rem = n & ((1<<dShift)-1);
                int hh = rem >> dhShift;
                int dd = rem & ((1<<dhShift)-1);
                int bb = m >> 10, tt = m & 1023;
                int Hn = 1 << (dShift - dhShift);
                float* dst = (which==0) ? Qd : ((which==1) ? Kd : Vd);
                dst[((((size_t)bb*Hn + hh)*L_ + tt) << dhShift) + dd] = v;
                continue;
            }
            size_t off = (size_t)m*N + n;
            if (mode == 1) v += R[off];
            else if (mode == 2) v = 0.5f*v*(1.0f + erff(v*0.70710678118654752f));
            if (mode == 3){
                if (flag[0]) ((bf16*)OutRaw)[off] = __float2bfloat16(v);
                else         ((float*)OutRaw)[off] = v;
            } else C[off] = v;
        }
    }
}

// ---------------- f16 MFMA GEMM: C = epilogue(A[M,K]f32 @ W[N,K]f32^T), f32 accum ----------------
// 128x128 tile, BK=32, 4 waves 2x2, wave = 4x4 MFMAs of 16x16x32_f16
__global__ __launch_bounds__(256) void k_mgemm(const float* __restrict__ A, const float* __restrict__ W,
        const float* __restrict__ R, float* __restrict__ C, void* __restrict__ OutRaw,
        const int* __restrict__ flag, int M, int N, int K, int mode,
        float* __restrict__ Qd, float* __restrict__ Kd, float* __restrict__ Vd,
        int dShift, int dhShift)
{
    __shared__ half8 As[4][128];     // [k-quad][m]
    __shared__ half8 Ws[4][128];     // [k-quad][n]
    int tid = threadIdx.x;
    int wave = tid >> 6, lane = tid & 63;
    int wr = wave >> 1, wc = wave & 1;
    int quad = lane >> 4, l15 = lane & 15;
    int bm = blockIdx.y * 128;
    int bn = blockIdx.x * 128;

    f32x4 acc[4][4] = {};

    int srow = tid >> 1;
    int skc = (tid & 1) * 2;
    const float* ap0 = A + (size_t)(bm + srow)*K + skc*8;
    int gn = bn + srow;
    const float* wp0 = W + (size_t)gn*K + skc*8;
    bool wok = (gn < N);

    for (int k0 = 0; k0 < K; k0 += 32){
        __syncthreads();
        {
            const float* ap = ap0 + k0;
            float4 u0 = *(const float4*)(ap);
            float4 u1 = *(const float4*)(ap+4);
            float4 u2 = *(const float4*)(ap+8);
            float4 u3 = *(const float4*)(ap+12);
            half8 h0, h1;
            h0[0]=(f16)u0.x; h0[1]=(f16)u0.y; h0[2]=(f16)u0.z; h0[3]=(f16)u0.w;
            h0[4]=(f16)u1.x; h0[5]=(f16)u1.y; h0[6]=(f16)u1.z; h0[7]=(f16)u1.w;
            h1[0]=(f16)u2.x; h1[1]=(f16)u2.y; h1[2]=(f16)u2.z; h1[3]=(f16)u2.w;
            h1[4]=(f16)u3.x; h1[5]=(f16)u3.y; h1[6]=(f16)u3.z; h1[7]=(f16)u3.w;
            As[skc][srow] = h0;
            As[skc+1][srow] = h1;
            half8 g0 = (half8)(f16)0.f, g1 = (half8)(f16)0.f;
            if (wok){
                const float* wp = wp0 + k0;
                float4 v0 = *(const float4*)(wp);
                float4 v1 = *(const float4*)(wp+4);
                float4 v2 = *(const float4*)(wp+8);
                float4 v3 = *(const float4*)(wp+12);
                g0[0]=(f16)v0.x; g0[1]=(f16)v0.y; g0[2]=(f16)v0.z; g0[3]=(f16)v0.w;
                g0[4]=(f16)v1.x; g0[5]=(f16)v1.y; g0[6]=(f16)v1.z; g0[7]=(f16)v1.w;
                g1[0]=(f16)v2.x; g1[1]=(f16)v2.y; g1[2]=(f16)v2.z; g1[3]=(f16)v2.w;
                g1[4]=(f16)v3.x; g1[5]=(f16)v3.y; g1[6]=(f16)v3.z; g1[7]=(f16)v3.w;
            }
            Ws[skc][srow] = g0;
            Ws[skc+1][srow] = g1;
        }
        __syncthreads();

        half8 af[4], wf[4];
        #pragma unroll
        for (int i=0;i<4;i++) af[i] = As[quad][wr*64 + i*16 + l15];
        #pragma unroll
        for (int j=0;j<4;j++) wf[j] = Ws[quad][wc*64 + j*16 + l15];
        #pragma unroll
        for (int i=0;i<4;i++)
            #pragma unroll
            for (int j=0;j<4;j++)
                acc[i][j] = __builtin_amdgcn_mfma_f32_16x16x32_f16(af[i], wf[j], acc[i][j], 0, 0, 0);
    }

    #pragma unroll
    for (int j=0;j<4;j++){
        int n = bn + wc*64 + j*16 + l15;
        if (n >= N) continue;
        #pragma unroll
        for (int i=0;i<4;i++){
            #pragma unroll
            for (int r=0;r<4;r++){
                int m = bm + wr*64 + i*16 + quad*4 + r;
                float v = acc[i][j][r];
                if (mode == 4){
                    int which = n >> dShift;
                    int rem = n & ((1<<dShift)-1);
                    int hh = rem >> dhShift;
                    int dd = rem & ((1<<dhShift)-1);
                    int bb = m >> 10, tt = m & 1023;
                    int Hn = 1 << (dShift - dhShift);
                    float* dst = (which==0) ? Qd : ((which==1) ? Kd : Vd);
                    dst[((((size_t)bb*Hn + hh)*L_ + tt) << dhShift) + dd] = v;
                    continue;
                }
                size_t off = (size_t)m*N + n;
                if (mode == 1) v += R[off];
                else if (mode == 2) v = 0.5f*v*(1.0f + erff(v*0.70710678118654752f));
                if (mode == 3){
                    if (flag[0]) ((bf16*)OutRaw)[off] = __float2bfloat16(v);
                    else         ((float*)OutRaw)[off] = v;
                } else C[off] = v;
            }
        }
    }
}

// ---------------- flash attention: block per (b,h, 64-query tile) ----------------
template<int DH>
__global__ __launch_bounds__(256) void k_flash(const float* __restrict__ Qh, const float* __restrict__ Kh,
        const float* __restrict__ Vh, float* __restrict__ out, const int* __restrict__ counts,
        float scale)
{
    constexpr int BQ = 64, BK = 64;
    constexpr int QS = BQ + 1;
    __shared__ float sQt[DH*QS];
    __shared__ float sKP[BK*QS];
    __shared__ float sV [BK*DH];

    int x = blockIdx.x;
    int b = x >> 2;
    int yy = blockIdx.y;
    int qt = (yy < 8) ? yy : 23 - yy;
    int q0 = qt * BQ;

    int tid = threadIdx.x;
    int tx = tid & 15, ty = tid >> 4;

    const float* Qb = Qh + ((size_t)x*L_)*DH;
    const float* Kb = Kh + ((size_t)x*L_)*DH;
    const float* Vb = Vh + ((size_t)x*L_)*DH;

    int kcap = counts ? counts[b] : L_;
    int klen = min(kcap, q0 + BQ);

    {
        const float4* src = (const float4*)(Qb + (size_t)q0*DH);
        for (int i = tid; i < BQ*DH/4; i += 256){
            float4 v = src[i];
            int t = (4*i) / DH, d = (4*i) % DH;
            sQt[(d+0)*QS + t] = v.x;
            sQt[(d+1)*QS + t] = v.y;
            sQt[(d+2)*QS + t] = v.z;
            sQt[(d+3)*QS + t] = v.w;
        }
    }

    float m[4], l[4], o[4][4];
    #pragma unroll
    for (int i=0;i<4;i++){ m[i] = -1e30f; l[i] = 0.f;
        #pragma unroll
        for (int j=0;j<4;j++) o[i][j] = 0.f; }

    for (int k0 = 0; k0 < klen; k0 += BK){
        __syncthreads();
        {
            const float4* ks = (const float4*)(Kb + (size_t)k0*DH);
            const float4* vs = (const float4*)(Vb + (size_t)k0*DH);
            for (int i = tid; i < BK*DH/4; i += 256){
                float4 kv = ks[i];
                int t = (4*i) / DH, d = (4*i) % DH;
                sKP[(d+0)*QS + t] = kv.x;
                sKP[(d+1)*QS + t] = kv.y;
                sKP[(d+2)*QS + t] = kv.z;
                sKP[(d+3)*QS + t] = kv.w;
                ((float4*)sV)[i] = vs[i];
            }
        }
        __syncthreads();

        float s[4][4] = {};
        #pragma unroll 4
        for (int d = 0; d < DH; d++){
            float4 qv = *(const float4*)&sQt[d*QS + ty*4];
            float4 kv = *(const float4*)&sKP[d*QS + tx*4];
            s[0][0] += qv.x*kv.x; s[0][1] += qv.x*kv.y; s[0][2] += qv.x*kv.z; s[0][3] += qv.x*kv.w;
            s[1][0] += qv.y*kv.x; s[1][1] += qv.y*kv.y; s[1][2] += qv.y*kv.z; s[1][3] += qv.y*kv.w;
            s[2][0] += qv.z*kv.x; s[2][1] += qv.z*kv.y; s[2][2] += qv.z*kv.z; s[2][3] += qv.z*kv.w;
            s[3][0] += qv.w*kv.x; s[3][1] += qv.w*kv.y; s[3][2] += qv.w*kv.z; s[3][3] += qv.w*kv.w;
        }
        bool needmask = (k0 >= q0) || (k0 + BK > kcap);
        #pragma unroll
        for (int i=0;i<4;i++){
            int q = q0 + ty*4 + i;
            #pragma unroll
            for (int j=0;j<4;j++){
                float v = s[i][j]*scale;
                if (needmask){
                    int k = k0 + tx*4 + j;
                    if (k > q || k >= kcap) v = -1e30f;
                }
                s[i][j] = v;
            }
        }
        __syncthreads();

        #pragma unroll
        for (int i=0;i<4;i++){
            float rm = fmaxf(fmaxf(s[i][0],s[i][1]), fmaxf(s[i][2],s[i][3]));
            rm = fmaxf(rm, __shfl_xor(rm, 1));
            rm = fmaxf(rm, __shfl_xor(rm, 2));
            rm = fmaxf(rm, __shfl_xor(rm, 4));
            rm = fmaxf(rm, __shfl_xor(rm, 8));
            float mn = fmaxf(m[i], rm);
            float al = __expf(m[i] - mn);
            float p0 = __expf(s[i][0]-mn), p1 = __expf(s[i][1]-mn);
            float p2 = __expf(s[i][2]-mn), p3 = __expf(s[i][3]-mn);
            float rs = p0+p1+p2+p3;
            rs += __shfl_xor(rs, 1);
            rs += __shfl_xor(rs, 2);
            rs += __shfl_xor(rs, 4);
            rs += __shfl_xor(rs, 8);
            l[i] = l[i]*al + rs;
            m[i] = mn;
            o[i][0]*=al; o[i][1]*=al; o[i][2]*=al; o[i][3]*=al;
            sKP[(tx*4+0)*QS + ty*4 + i] = p0;
            sKP[(tx*4+1)*QS + ty*4 + i] = p1;
            sKP[(tx*4+2)*QS + ty*4 + i] = p2;
            sKP[(tx*4+3)*QS + ty*4 + i] = p3;
        }
        __syncthreads();

        if (tx*4 < DH){
            #pragma unroll 4
            for (int k = 0; k < BK; k++){
                float4 pv = *(const float4*)&sKP[k*QS + ty*4];
                float4 vv = *(const float4*)&sV[k*DH + tx*4];
                o[0][0] += pv.x*vv.x; o[0][1] += pv.x*vv.y; o[0][2] += pv.x*vv.z; o[0][3] += pv.x*vv.w;
                o[1][0] += pv.y*vv.x; o[1][1] += pv.y*vv.y; o[1][2] += pv.y*vv.z; o[1][3] += pv.y*vv.w;
                o[2][0] += pv.z*vv.x; o[2][1] += pv.z*vv.y; o[2][2] += pv.z*vv.z; o[2][3] += pv.z*vv.w;
                o[3][0] += pv.w*vv.x; o[3][1] += pv.w*vv.y; o[3][2] += pv.w*vv.z; o[3][3] += pv.w*vv.w;
            }
        }
    }

    if (tx*4 < DH){
        int h = x & 3;
        #pragma unroll
        for (int i=0;i<4;i++){
            float inv = 1.0f / l[i];
            int q = q0 + ty*4 + i;
            float4 r = make_float4(o[i][0]*inv, o[i][1]*inv, o[i][2]*inv, o[i][3]*inv);
            *(float4*)&out[((size_t)b*L_ + q)*(4*DH) + h*DH + tx*4] = r;
        }
    }
}

// ---------------- router ----------------
__global__ __launch_bounds__(64) void k_router(const float* __restrict__ Q, const float* __restrict__ Kr,
        float* __restrict__ p, float* __restrict__ bh)
{
    int idx = blockIdx.x;
    int t = idx & (L_-1);
    int lane = threadIdx.x;
    float pv;
    if (t == 0){ pv = 1.0f; }
    else {
        const float* qr = Q  + (size_t)idx*DENC;
        const float* kr = Kr + (size_t)(idx-1)*DENC;
        float qq=0.f, kk=0.f, qk=0.f;
        #pragma unroll
        for (int j=0;j<2;j++){
            float qv = qr[lane + j*64], kv = kr[lane + j*64];
            qq += qv*qv; kk += kv*kv; qk += qv*kv;
        }
        #pragma unroll
        for (int o=32;o>=1;o>>=1){ qq += __shfl_xor(qq,o); kk += __shfl_xor(kk,o); qk += __shfl_xor(qk,o); }
        float cosv = qk / (fmaxf(sqrtf(qq),1e-12f)*fmaxf(sqrtf(kk),1e-12f));
        pv = 0.5f*(1.0f - cosv);
        pv = fminf(fmaxf(pv, 0.0f), 1.0f);
    }
    if (lane == 0){ p[idx] = pv; bh[idx] = (pv >= 0.5f) ? 1.0f : 0.0f; }
}

// ---------------- per-batch cumsum via wave scan ----------------
__global__ __launch_bounds__(64) void k_seq(const float* __restrict__ bh, int* __restrict__ cidx,
                      int* __restrict__ dest, int* __restrict__ counts){
    int b = blockIdx.x;
    int lane = threadIdx.x;
    int base = b*L_ + lane*16;
    int h[16];
    int cnt = 0;
    #pragma unroll
    for (int j=0;j<16;j++){ h[j] = bh[base+j] > 0.5f; cnt += h[j]; }
    int inc = cnt;
    #pragma unroll
    for (int o=1;o<64;o<<=1){ int nb = __shfl_up(inc, o); if (lane >= o) inc += nb; }
    int run = inc - cnt;
    #pragma unroll
    for (int j=0;j<16;j++){
        run += h[j];
        int ci = run - 1; if (ci < 0) ci = 0;
        cidx[base+j] = ci;
        dest[base+j] = h[j] ? (run-1) : L_;
    }
    if (lane == 63) counts[b] = inc;
}

__global__ void k_zero(float* p, int n){ int i = blockIdx.x*256+threadIdx.x; if (i < n) p[i] = 0.f; }

__global__ void k_scatter(const float* __restrict__ x, const float* __restrict__ p,
        const int* __restrict__ dest, const float* __restrict__ bh,
        float* __restrict__ comp, float* __restrict__ pcomp)
{
    int i = blockIdx.x;
    int d = threadIdx.x;
    int b = i >> 10;
    if (bh[i] > 0.5f){
        int ds = dest[i];
        comp[((size_t)b*L_ + ds)*DENC + d] = x[(size_t)i*DENC + d];
        if (d == 0) pcomp[b*L_ + ds] = p[i];
    }
}

__global__ __launch_bounds__(256) void k_reduce(const float* __restrict__ p, const float* __restrict__ bh,
                                                float* __restrict__ acc){
    __shared__ float sp[256], sb[256];
    int tid = threadIdx.x;
    float s1=0.f, s2=0.f;
    for (int i = blockIdx.x*256 + tid; i < BL; i += gridDim.x*256){ s1 += p[i]; s2 += bh[i]; }
    sp[tid]=s1; sb[tid]=s2; __syncthreads();
    for (int o=128;o>=1;o>>=1){ if (tid<o){ sp[tid]+=sp[tid+o]; sb[tid]+=sb[tid+o]; } __syncthreads(); }
    if (tid==0){ atomicAdd(&acc[0], sp[0]); atomicAdd(&acc[1], sb[0]); }
}

// ---------------- chunk EMA scan ----------------
__global__ __launch_bounds__(64) void k_ema(const float* __restrict__ z, const float* __restrict__ pcomp,
                                            float* __restrict__ zbar){
    int gid = blockIdx.x*64 + threadIdx.x;
    int b = gid >> 7, d = gid & 127;
    const float* zb = z    + (size_t)b*L_*DENC + d;
    float*       ob = zbar + (size_t)b*L_*DENC + d;
    float prev = 0.f;
    for (int t = 0; t < L_; t++){
        float pc = pcomp[b*L_ + t];
        pc = fminf(fmaxf(pc, 1e-4f), 1.0f-1e-4f);
        float zv = zb[(size_t)t*DENC];
        float a  = (t==0) ? 0.0f : (1.0f - pc);
        float bv = (t==0) ? zv : pc*zv;
        prev = a*prev + bv;
        ob[(size_t)t*DENC] = prev;
    }
}

__global__ void k_combine(float* __restrict__ x, const float* __restrict__ zbar, const int* __restrict__ cidx){
    int i = blockIdx.x*256 + threadIdx.x;
    int row = i >> 7, d = i & 127;
    int b = row >> 10;
    int ci = cidx[row];
    x[i] += zbar[((size_t)b*L_ + ci)*DENC + d];
}

__global__ void k_loss(const float* __restrict__ acc, void* __restrict__ out, const int* __restrict__ flag){
    float G = acc[0] / (float)BL;
    float F = acc[1] / (float)BL;
    float ratio = 1.2f*(5.0f*F*G + (1.0f-F)*(1.0f-G));
    if (flag[0]) ((bf16*)out)[(size_t)BL*VOCAB] = __float2bfloat16(ratio);
    else         ((float*)out)[(size_t)BL*VOCAB] = ratio;
}

// =========================================================================
extern "C" void kernel_launch(void* const* d_in, const int* in_sizes, int n_in,
                              void* d_out, int out_size, void* d_ws, size_t ws_size,
                              hipStream_t stream) {
    (void)out_size; (void)ws_size;
    const int* byte_ids = (const int*)d_in[0];

    float* ws = (float*)d_ws;
    size_t off = 0;
    int* FLAG = (int*)ws; off += 16;
    float* W32 = ws + off;

    k_detect<<<1, 64, 0, stream>>>(d_in[1], FLAG);

    CvtArgs ca;
    const float* w32[32];
    unsigned woff = 0;
    for (int i = 1; i < n_in && i < 32; i++){
        w32[i] = W32 + woff;
        ca.src[i-1] = d_in[i];
        ca.offs[i-1] = woff;
        woff += (unsigned)in_sizes[i];
    }
    ca.offs[31] = woff;
    k_cvt_all<<<2048, 256, 0, stream>>>(ca, W32, (int)woff, FLAG);
    off += woff;

    const float* embed    = w32[1];
    const float* wq       = w32[2];
    const float* wk       = w32[3];
    const float* proj_up  = w32[4];
    const float* proj_dn  = w32[5];
    const float* norm_w   = w32[6];
    const float* norm_b   = w32[7];
    const float* enc_ln1w = w32[8];
    const float* enc_ln1b = w32[9];
    const float* enc_qkv  = w32[10];
    const float* enc_wo   = w32[11];
    const float* enc_ln2w = w32[12];
    const float* enc_ln2b = w32[13];
    const float* enc_w1   = w32[14];
    const float* enc_w2   = w32[15];
    const float* main_ln1w= w32[16];
    const float* main_ln1b= w32[17];
    const float* main_qkv = w32[18];
    const float* main_wo  = w32[19];
    const float* main_ln2w= w32[20];
    const float* main_ln2b= w32[21];
    const float* main_w1  = w32[22];
    const float* main_w2  = w32[23];
    const float* dec_ln1w = w32[24];
    const float* dec_ln1b = w32[25];
    const float* dec_qkv  = w32[26];
    const float* dec_wo   = w32[27];
    const float* dec_ln2w = w32[28];
    const float* dec_ln2b = w32[29];
    const float* dec_w1   = w32[30];
    const float* dec_w2   = w32[31];

    float* X    = ws + off; off += (size_t)BL*DENC;
    float* LN   = ws + off; off += (size_t)BL*DMAIN;
    float* QKV  = ws + off; off += (size_t)BL*3*DMAIN;
    float* ATT  = ws + off; off += (size_t)BL*DMAIN;
    float* H    = ws + off; off += (size_t)BL*2*DMAIN;
    float* Z    = ws + off; off += (size_t)BL*DMAIN;
    float* COMP = ws + off; off += (size_t)BL*DENC;
    float* P    = ws + off; off += BL;
    float* BH   = ws + off; off += BL;
    float* PCOMP= ws + off; off += BL;
    float* ACC  = ws + off; off += 8;
    int* CIDX   = (int*)(ws + off); off += BL;
    int* DEST   = (int*)(ws + off); off += BL;
    int* COUNTS = (int*)(ws + off); off += 64;
    float* TMP  = H;
    float* ZDN  = QKV;
    float* ZBAR = QKV + (size_t)BL*DENC;

    // f32 vector GEMM (router-sensitive path)
    auto gemm32 = [&](const float* A, const float* W, const float* R, float* C, void* Ob,
                    int N, int K, int mode){
        dim3 g((N+GBN-1)/GBN, BL/GBM);
        k_gemm<<<g, 256, 0, stream>>>(A, W, R, C, Ob, FLAG, BL, N, K, mode,
                                      nullptr, nullptr, nullptr, 0, 0);
    };
    // f16 MFMA GEMM
    auto gemm16 = [&](const float* A, const float* W, const float* R, float* C, void* Ob,
                    int N, int K, int mode){
        dim3 g((N+127)/128, BL/128);
        k_mgemm<<<g, 256, 0, stream>>>(A, W, R, C, Ob, FLAG, BL, N, K, mode,
                                       nullptr, nullptr, nullptr, 0, 0);
    };
    auto gemm_qkv = [&](const float* A, const float* W, int D, int dh, bool mfma){
        int N = 3*D;
        int dS = (D == 128) ? 7 : 8;
        int dhS = (dh == 32) ? 5 : 6;
        float* Qh = QKV;
        float* Kh = QKV + (size_t)BL*D;
        float* Vh = QKV + (size_t)2*BL*D;
        if (mfma){
            dim3 g(N/128, BL/128);
            k_mgemm<<<g, 256, 0, stream>>>(A, W, nullptr, nullptr, nullptr, FLAG, BL, N, D, 4,
                                           Qh, Kh, Vh, dS, dhS);
        } else {
            dim3 g(N/GBN, BL/GBM);
            k_gemm<<<g, 256, 0, stream>>>(A, W, nullptr, nullptr, nullptr, FLAG, BL, N, D, 4,
                                          Qh, Kh, Vh, dS, dhS);
        }
    };

    auto block128 = [&](float* Xs, const float* l1w, const float* l1b, const float* qkvw, const float* wo,
                        const float* l2w, const float* l2b, const float* w1, const float* w2, bool mfma){
        k_ln<128><<<BL,64,0,stream>>>(Xs, l1w, l1b, LN);
        gemm_qkv(LN, qkvw, DENC, 32, mfma);
        k_flash<32><<<dim3(B_*NHEADS,16),256,0,stream>>>(QKV, QKV+(size_t)BL*DENC, QKV+(size_t)2*BL*DENC,
                                                         ATT, nullptr, 0.17677669529663687f);
        if (mfma){
            gemm16(ATT, wo, Xs, Xs, nullptr, DENC, DENC, 1);
            k_ln<128><<<BL,64,0,stream>>>(Xs, l2w, l2b, LN);
            gemm16(LN, w1, nullptr, H, nullptr, 2*DENC, DENC, 2);
            gemm16(H, w2, Xs, Xs, nullptr, DENC, 2*DENC, 1);
        } else {
            gemm32(ATT, wo, Xs, Xs, nullptr, DENC, DENC, 1);
            k_ln<128><<<BL,64,0,stream>>>(Xs, l2w, l2b, LN);
            gemm32(LN, w1, nullptr, H, nullptr, 2*DENC, DENC, 2);
            gemm32(H, w2, Xs, Xs, nullptr, DENC, 2*DENC, 1);
        }
    };
    auto block256 = [&](float* Xs, const float* l1w, const float* l1b, const float* qkvw, const float* wo,
                        const float* l2w, const float* l2b, const float* w1, const float* w2){
        k_ln<256><<<BL,64,0,stream>>>(Xs, l1w, l1b, LN);
        gemm_qkv(LN, qkvw, DMAIN, 64, true);
        k_flash<64><<<dim3(B_*NHEADS,16),256,0,stream>>>(QKV, QKV+(size_t)BL*DMAIN, QKV+(size_t)2*BL*DMAIN,
                                                         ATT, COUNTS, 0.125f);
        gemm16(ATT, wo, Xs, Xs, nullptr, DMAIN, DMAIN, 1);
        k_ln<256><<<BL,64,0,stream>>>(Xs, l2w, l2b, LN);
        gemm16(LN, w1, nullptr, H, nullptr, 2*DMAIN, DMAIN, 2);
        gemm16(H, w2, Xs, Xs, nullptr, DMAIN, 2*DMAIN, 1);
    };

    // ---- embed + encoder (f32: router decisions are sensitive) ----
    k_embed<<<BL*DENC/256, 256, 0, stream>>>(byte_ids, embed, X);
    for (int i = 0; i < 3; i++)
        block128(X, enc_ln1w + i*DENC, enc_ln1b + i*DENC, enc_qkv + (size_t)i*3*DENC*DENC,
                 enc_wo + (size_t)i*DENC*DENC, enc_ln2w + i*DENC, enc_ln2b + i*DENC,
                 enc_w1 + (size_t)i*2*DENC*DENC, enc_w2 + (size_t)i*2*DENC*DENC, false);

    // ---- routing (f32) ----
    gemm32(X, wq, nullptr, ATT, nullptr, DENC, DENC, 0);
    gemm32(X, wk, nullptr, TMP, nullptr, DENC, DENC, 0);
    k_router<<<BL, 64, 0, stream>>>(ATT, TMP, P, BH);
    k_seq<<<B_, 64, 0, stream>>>(BH, CIDX, DEST, COUNTS);
    k_zero<<<(BL*DENC+255)/256, 256, 0, stream>>>(COMP, BL*DENC);
    k_zero<<<(BL+255)/256, 256, 0, stream>>>(PCOMP, BL);
    k_zero<<<1, 256, 0, stream>>>(ACC, 8);
    k_scatter<<<BL, 128, 0, stream>>>(X, P, DEST, BH, COMP, PCOMP);
    k_reduce<<<8, 256, 0, stream>>>(P, BH, ACC);

    // ---- main stack on compressed (f16 MFMA) ----
    gemm16(COMP, proj_up, nullptr, Z, nullptr, DMAIN, DENC, 0);
    for (int i = 0; i < 6; i++)
        block256(Z, main_ln1w + i*DMAIN, main_ln1b + i*DMAIN, main_qkv + (size_t)i*3*DMAIN*DMAIN,
                 main_wo + (size_t)i*DMAIN*DMAIN, main_ln2w + i*DMAIN, main_ln2b + i*DMAIN,
                 main_w1 + (size_t)i*2*DMAIN*DMAIN, main_w2 + (size_t)i*2*DMAIN*DMAIN);
    gemm16(Z, proj_dn, nullptr, ZDN, nullptr, DENC, DMAIN, 0);

    // ---- EMA + dechunk combine ----
    k_ema<<<B_*DENC/64, 64, 0, stream>>>(ZDN, PCOMP, ZBAR);
    k_combine<<<BL*DENC/256, 256, 0, stream>>>(X, ZBAR, CIDX);

    // ---- decoder (f16 MFMA) ----
    for (int i = 0; i < 3; i++)
        block128(X, dec_ln1w + i*DENC, dec_ln1b + i*DENC, dec_qkv + (size_t)i*3*DENC*DENC,
                 dec_wo + (size_t)i*DENC*DENC, dec_ln2w + i*DENC, dec_ln2b + i*DENC,
                 dec_w1 + (size_t)i*2*DENC*DENC, dec_w2 + (size_t)i*2*DENC*DENC, true);

    // ---- final LN + tied head + loss ----
    k_ln<128><<<BL,64,0,stream>>>(X, norm_w, norm_b, LN);
    gemm16(LN, embed, nullptr, nullptr, d_out, VOCAB, DENC, 3);
    k_loss<<<1,1,0,stream>>>(ACC, d_out, FLAG);
}

// Round 5
// 2324.607 us; speedup vs baseline: 2.4132x; 1.0984x over previous
//
#include <hip/hip_runtime.h>
#include <hip/hip_bf16.h>

#define B_ 8
#define L_ 1024
#define BL (B_*L_)
#define DENC 128
#define DMAIN 256
#define VOCAB 260
#define NHEADS 4

typedef __hip_bfloat16 bf16;
typedef _Float16 f16;
typedef f16 half8 __attribute__((ext_vector_type(8)));
typedef float f32x4 __attribute__((ext_vector_type(4)));

// ---------------- dtype detector: flag=1 if inputs are bf16, 0 if f32 ----------------
__global__ __launch_bounds__(64) void k_detect(const void* __restrict__ emb, int* __restrict__ flag){
    int lane = threadIdx.x;
    const unsigned short* u = (const unsigned short*)emb;
    int bad = 0;
    #pragma unroll
    for (int j = 0; j < 4; j++){
        unsigned short h = u[lane + 64*j];
        bf16 t = *(const bf16*)&h;
        float v = __bfloat162float(t);
        if (!(fabsf(v) < 1e4f)) bad++;
    }
    #pragma unroll
    for (int o = 32; o >= 1; o >>= 1) bad += __shfl_xor(bad, o);
    if (lane == 0) flag[0] = (bad == 0) ? 1 : 0;
}

// ---------------- fused convert of all 31 float inputs ----------------
struct CvtArgs {
    const void* src[31];
    unsigned offs[32];
};
__global__ void k_cvt_all(CvtArgs a, float* __restrict__ dst, int total, const int* __restrict__ flag){
    int isbf = flag[0];
    for (int i = blockIdx.x*256 + threadIdx.x; i < total; i += gridDim.x*256){
        int lo = 0, hi = 30;
        while (lo < hi){ int mid = (lo+hi+1)>>1; if (a.offs[mid] <= (unsigned)i) lo = mid; else hi = mid-1; }
        int j = i - (int)a.offs[lo];
        dst[i] = isbf ? __bfloat162float(((const bf16*)a.src[lo])[j])
                      : ((const float*)a.src[lo])[j];
    }
}

// ---------------- embed gather ----------------
__global__ void k_embed(const int* __restrict__ ids, const float* __restrict__ emb, float* __restrict__ x){
    int i = blockIdx.x*256 + threadIdx.x;
    int row = i >> 7, d = i & 127;
    x[i] = emb[ids[row]*DENC + d];
}

// ---------------- layernorm (one wave per row) ----------------
template<int D>
__global__ __launch_bounds__(64) void k_ln(const float* __restrict__ x, const float* __restrict__ w,
                                           const float* __restrict__ b, float* __restrict__ y){
    int row = blockIdx.x;
    int lane = threadIdx.x;
    const float* xr = x + (size_t)row*D;
    float v[D/64];
    float s = 0.f;
    #pragma unroll
    for (int j=0;j<D/64;j++){ v[j] = xr[lane + j*64]; s += v[j]; }
    #pragma unroll
    for (int o=32;o>=1;o>>=1) s += __shfl_xor(s,o);
    float mu = s / (float)D;
    float s2 = 0.f;
    #pragma unroll
    for (int j=0;j<D/64;j++){ float dd = v[j]-mu; s2 += dd*dd; }
    #pragma unroll
    for (int o=32;o>=1;o>>=1) s2 += __shfl_xor(s2,o);
    float inv = rsqrtf(s2/(float)D + 1e-5f);
    float* yr = y + (size_t)row*D;
    #pragma unroll
    for (int j=0;j<D/64;j++){
        int d = lane + j*64;
        yr[d] = (v[j]-mu)*inv*w[d] + b[d];
    }
}

// ---------------- f32 vector GEMM (router wq/wk only) ----------------
#define GBM 64
#define GBN 64
#define GBK 32
__global__ __launch_bounds__(256) void k_gemm(const float* __restrict__ A, const float* __restrict__ W,
        float* __restrict__ C, int M, int N, int K)
{
    __shared__ float As[GBK][GBM+4];
    __shared__ float Ws[GBK][GBN+4];
    int tid = threadIdx.x;
    int bm = blockIdx.y * GBM;
    int bn = blockIdx.x * GBN;
    int tx = tid & 15, ty = tid >> 4;
    float acc[4][4] = {};
    for (int k0 = 0; k0 < K; k0 += GBK){
        #pragma unroll
        for (int i = tid; i < GBM*GBK; i += 256){
            int m = i >> 5, kk = i & 31;
            As[kk][m] = A[(size_t)(bm+m)*K + k0 + kk];
        }
        #pragma unroll
        for (int i = tid; i < GBN*GBK; i += 256){
            int n = i >> 5, kk = i & 31;
            int gn = bn + n;
            Ws[kk][n] = (gn < N) ? W[(size_t)gn*K + k0 + kk] : 0.0f;
        }
        __syncthreads();
        #pragma unroll
        for (int kk = 0; kk < GBK; kk++){
            float a0[4], w0[4];
            *(float4*)a0 = *(const float4*)&As[kk][ty*4];
            *(float4*)w0 = *(const float4*)&Ws[kk][tx*4];
            #pragma unroll
            for (int i=0;i<4;i++)
                #pragma unroll
                for (int j=0;j<4;j++) acc[i][j] += a0[i]*w0[j];
        }
        __syncthreads();
    }
    #pragma unroll
    for (int i=0;i<4;i++){
        int m = bm + ty*4 + i;
        #pragma unroll
        for (int j=0;j<4;j++){
            int n = bn + tx*4 + j;
            if (n < N) C[(size_t)m*N + n] = acc[i][j];
        }
    }
}

// ---------------- f16 MFMA GEMM: C = epilogue(A[M,K]f32 @ W[N,K]f32^T), f32 accum ----------------
// modes: 0 plain, 1 +R residual, 2 gelu, 3 out-store (bf16/f32 per flag), 4 split-head QKV
__global__ __launch_bounds__(256) void k_mgemm(const float* __restrict__ A, const float* __restrict__ W,
        const float* __restrict__ R, float* __restrict__ C, void* __restrict__ OutRaw,
        const int* __restrict__ flag, int M, int N, int K, int mode,
        float* __restrict__ Qd, float* __restrict__ Kd, float* __restrict__ Vd,
        int dShift, int dhShift)
{
    __shared__ half8 As[4][128];
    __shared__ half8 Ws[4][128];
    int tid = threadIdx.x;
    int wave = tid >> 6, lane = tid & 63;
    int wr = wave >> 1, wc = wave & 1;
    int quad = lane >> 4, l15 = lane & 15;
    int bm = blockIdx.y * 128;
    int bn = blockIdx.x * 128;

    f32x4 acc[4][4] = {};

    int srow = tid >> 1;
    int skc = (tid & 1) * 2;
    const float* ap0 = A + (size_t)(bm + srow)*K + skc*8;
    int gn = bn + srow;
    const float* wp0 = W + (size_t)gn*K + skc*8;
    bool wok = (gn < N);

    for (int k0 = 0; k0 < K; k0 += 32){
        __syncthreads();
        {
            const float* ap = ap0 + k0;
            float4 u0 = *(const float4*)(ap);
            float4 u1 = *(const float4*)(ap+4);
            float4 u2 = *(const float4*)(ap+8);
            float4 u3 = *(const float4*)(ap+12);
            half8 h0, h1;
            h0[0]=(f16)u0.x; h0[1]=(f16)u0.y; h0[2]=(f16)u0.z; h0[3]=(f16)u0.w;
            h0[4]=(f16)u1.x; h0[5]=(f16)u1.y; h0[6]=(f16)u1.z; h0[7]=(f16)u1.w;
            h1[0]=(f16)u2.x; h1[1]=(f16)u2.y; h1[2]=(f16)u2.z; h1[3]=(f16)u2.w;
            h1[4]=(f16)u3.x; h1[5]=(f16)u3.y; h1[6]=(f16)u3.z; h1[7]=(f16)u3.w;
            As[skc][srow] = h0;
            As[skc+1][srow] = h1;
            half8 g0 = (half8)(f16)0.f, g1 = (half8)(f16)0.f;
            if (wok){
                const float* wp = wp0 + k0;
                float4 v0 = *(const float4*)(wp);
                float4 v1 = *(const float4*)(wp+4);
                float4 v2 = *(const float4*)(wp+8);
                float4 v3 = *(const float4*)(wp+12);
                g0[0]=(f16)v0.x; g0[1]=(f16)v0.y; g0[2]=(f16)v0.z; g0[3]=(f16)v0.w;
                g0[4]=(f16)v1.x; g0[5]=(f16)v1.y; g0[6]=(f16)v1.z; g0[7]=(f16)v1.w;
                g1[0]=(f16)v2.x; g1[1]=(f16)v2.y; g1[2]=(f16)v2.z; g1[3]=(f16)v2.w;
                g1[4]=(f16)v3.x; g1[5]=(f16)v3.y; g1[6]=(f16)v3.z; g1[7]=(f16)v3.w;
            }
            Ws[skc][srow] = g0;
            Ws[skc+1][srow] = g1;
        }
        __syncthreads();

        half8 af[4], wf[4];
        #pragma unroll
        for (int i=0;i<4;i++) af[i] = As[quad][wr*64 + i*16 + l15];
        #pragma unroll
        for (int j=0;j<4;j++) wf[j] = Ws[quad][wc*64 + j*16 + l15];
        #pragma unroll
        for (int i=0;i<4;i++)
            #pragma unroll
            for (int j=0;j<4;j++)
                acc[i][j] = __builtin_amdgcn_mfma_f32_16x16x32_f16(af[i], wf[j], acc[i][j], 0, 0, 0);
    }

    #pragma unroll
    for (int j=0;j<4;j++){
        int n = bn + wc*64 + j*16 + l15;
        if (n >= N) continue;
        #pragma unroll
        for (int i=0;i<4;i++){
            #pragma unroll
            for (int r=0;r<4;r++){
                int m = bm + wr*64 + i*16 + quad*4 + r;
                float v = acc[i][j][r];
                if (mode == 4){
                    int which = n >> dShift;
                    int rem = n & ((1<<dShift)-1);
                    int hh = rem >> dhShift;
                    int dd = rem & ((1<<dhShift)-1);
                    int bb = m >> 10, tt = m & 1023;
                    int Hn = 1 << (dShift - dhShift);
                    float* dst = (which==0) ? Qd : ((which==1) ? Kd : Vd);
                    dst[((((size_t)bb*Hn + hh)*L_ + tt) << dhShift) + dd] = v;
                    continue;
                }
                size_t off = (size_t)m*N + n;
                if (mode == 1) v += R[off];
                else if (mode == 2) v = 0.5f*v*(1.0f + erff(v*0.70710678118654752f));
                if (mode == 3){
                    if (flag[0]) ((bf16*)OutRaw)[off] = __float2bfloat16(v);
                    else         ((float*)OutRaw)[off] = v;
                } else C[off] = v;
            }
        }
    }
}

// ---------------- flash attention v2: block per (b,h, 32-query tile), BK=64 ----------------
// 2q x 4k microtile per lane; aligned LDS (16B row strides); P in [q][k] layout (conflict-free)
template<int DH>
__global__ __launch_bounds__(256) void k_flash(const float* __restrict__ Qh, const float* __restrict__ Kh,
        const float* __restrict__ Vh, float* __restrict__ out, const int* __restrict__ counts,
        float scale)
{
    constexpr int BQ = 32, BK = 64;
    constexpr int QS = 36;                 // Qt row stride (floats), 144B: 16B aligned
    constexpr int KS = 68;                 // Kt/P row stride, 272B: 16B aligned
    __shared__ float sQt[DH*QS];           // Q transposed [d][q]
    __shared__ float sKtP[(DH>32?DH:32)*KS]; // K^T [d][k] during QK; P [q][k] during PV
    __shared__ float sV [BK*DH];           // V row-major [k][d]

    int x = blockIdx.x;                    // b*NHEADS + h
    int b = x >> 2, h = x & 3;
    int yy = blockIdx.y;
    int qt = (yy < 16) ? yy : 47 - yy;     // pair low/high triangle tiles
    int q0 = qt * BQ;

    int tid = threadIdx.x;
    int tx = tid & 15, ty = tid >> 4;      // tx: k-quad, ty: q-pair (0..15)

    const float* Qb = Qh + ((size_t)x*L_)*DH;
    const float* Kb = Kh + ((size_t)x*L_)*DH;
    const float* Vb = Vh + ((size_t)x*L_)*DH;

    int kcap = counts ? counts[b] : L_;
    int klen = min(kcap, q0 + BQ);

    // stage Q transposed
    {
        const float4* src = (const float4*)(Qb + (size_t)q0*DH);
        for (int i = tid; i < BQ*DH/4; i += 256){
            float4 v = src[i];
            int t = (4*i) / DH, d = (4*i) % DH;
            sQt[(d+0)*QS + t] = v.x;
            sQt[(d+1)*QS + t] = v.y;
            sQt[(d+2)*QS + t] = v.z;
            sQt[(d+3)*QS + t] = v.w;
        }
    }

    float m[2] = {-1e30f,-1e30f}, l[2] = {0.f,0.f};
    float o[2][4] = {};
    int q[2] = {q0 + 2*ty, q0 + 2*ty + 1};

    for (int k0 = 0; k0 < klen; k0 += BK){
        __syncthreads();                   // prev PV done (Qt staged on first iter)
        {
            const float4* ks = (const float4*)(Kb + (size_t)k0*DH);
            const float4* vs = (const float4*)(Vb + (size_t)k0*DH);
            for (int i = tid; i < BK*DH/4; i += 256){
                float4 kv = ks[i];
                int t = (4*i) / DH, d = (4*i) % DH;
                sKtP[(d+0)*KS + t] = kv.x;
                sKtP[(d+1)*KS + t] = kv.y;
                sKtP[(d+2)*KS + t] = kv.z;
                sKtP[(d+3)*KS + t] = kv.w;
                ((float4*)sV)[i] = vs[i];
            }
        }
        __syncthreads();

        // S microtile [2q][4k]
        float s[2][4] = {};
        #pragma unroll 4
        for (int d = 0; d < DH; d++){
            float2 qv = *(const float2*)&sQt[d*QS + 2*ty];
            float4 kv = *(const float4*)&sKtP[d*KS + 4*tx];
            s[0][0] += qv.x*kv.x; s[0][1] += qv.x*kv.y; s[0][2] += qv.x*kv.z; s[0][3] += qv.x*kv.w;
            s[1][0] += qv.y*kv.x; s[1][1] += qv.y*kv.y; s[1][2] += qv.y*kv.z; s[1][3] += qv.y*kv.w;
        }
        // mask + online softmax (registers only; reduction across the 16 tx lanes)
        float4 pr[2];
        #pragma unroll
        for (int i=0;i<2;i++){
            #pragma unroll
            for (int j=0;j<4;j++){
                float v = s[i][j]*scale;
                int k = k0 + tx*4 + j;
                if (k > q[i] || k >= kcap) v = -1e30f;
                s[i][j] = v;
            }
            float rm = fmaxf(fmaxf(s[i][0],s[i][1]), fmaxf(s[i][2],s[i][3]));
            rm = fmaxf(rm, __shfl_xor(rm, 1));
            rm = fmaxf(rm, __shfl_xor(rm, 2));
            rm = fmaxf(rm, __shfl_xor(rm, 4));
            rm = fmaxf(rm, __shfl_xor(rm, 8));
            float mn = fmaxf(m[i], rm);
            float al = __expf(m[i] - mn);
            float p0 = __expf(s[i][0]-mn), p1 = __expf(s[i][1]-mn);
            float p2 = __expf(s[i][2]-mn), p3 = __expf(s[i][3]-mn);
            float rs = p0+p1+p2+p3;
            rs += __shfl_xor(rs, 1);
            rs += __shfl_xor(rs, 2);
            rs += __shfl_xor(rs, 4);
            rs += __shfl_xor(rs, 8);
            l[i] = l[i]*al + rs;
            m[i] = mn;
            o[i][0]*=al; o[i][1]*=al; o[i][2]*=al; o[i][3]*=al;
            pr[i] = make_float4(p0,p1,p2,p3);
        }
        __syncthreads();                   // everyone done reading Kt
        *(float4*)&sKtP[(2*ty+0)*KS + 4*tx] = pr[0];
        *(float4*)&sKtP[(2*ty+1)*KS + 4*tx] = pr[1];
        __syncthreads();

        // PV: o[2q][4d], d-cols owned by tx (only tx*4 < DH active)
        if (4*tx < DH){
            #pragma unroll 2
            for (int kc = 0; kc < BK; kc += 4){
                float4 p0 = *(const float4*)&sKtP[(2*ty+0)*KS + kc];
                float4 p1 = *(const float4*)&sKtP[(2*ty+1)*KS + kc];
                float pa0[4] = {p0.x,p0.y,p0.z,p0.w};
                float pa1[4] = {p1.x,p1.y,p1.z,p1.w};
                #pragma unroll
                for (int jk=0;jk<4;jk++){
                    float4 vv = *(const float4*)&sV[(kc+jk)*DH + 4*tx];
                    o[0][0] += pa0[jk]*vv.x; o[0][1] += pa0[jk]*vv.y;
                    o[0][2] += pa0[jk]*vv.z; o[0][3] += pa0[jk]*vv.w;
                    o[1][0] += pa1[jk]*vv.x; o[1][1] += pa1[jk]*vv.y;
                    o[1][2] += pa1[jk]*vv.z; o[1][3] += pa1[jk]*vv.w;
                }
            }
        }
    }

    if (4*tx < DH){
        #pragma unroll
        for (int i=0;i<2;i++){
            float inv = 1.0f / l[i];
            float4 r = make_float4(o[i][0]*inv, o[i][1]*inv, o[i][2]*inv, o[i][3]*inv);
            *(float4*)&out[((size_t)b*L_ + q[i])*(4*DH) + h*DH + 4*tx] = r;
        }
    }
}

// ---------------- router ----------------
__global__ __launch_bounds__(64) void k_router(const float* __restrict__ Q, const float* __restrict__ Kr,
        float* __restrict__ p, float* __restrict__ bh)
{
    int idx = blockIdx.x;
    int t = idx & (L_-1);
    int lane = threadIdx.x;
    float pv;
    if (t == 0){ pv = 1.0f; }
    else {
        const float* qr = Q  + (size_t)idx*DENC;
        const float* kr = Kr + (size_t)(idx-1)*DENC;
        float qq=0.f, kk=0.f, qk=0.f;
        #pragma unroll
        for (int j=0;j<2;j++){
            float qv = qr[lane + j*64], kv = kr[lane + j*64];
            qq += qv*qv; kk += kv*kv; qk += qv*kv;
        }
        #pragma unroll
        for (int o=32;o>=1;o>>=1){ qq += __shfl_xor(qq,o); kk += __shfl_xor(kk,o); qk += __shfl_xor(qk,o); }
        float cosv = qk / (fmaxf(sqrtf(qq),1e-12f)*fmaxf(sqrtf(kk),1e-12f));
        pv = 0.5f*(1.0f - cosv);
        pv = fminf(fmaxf(pv, 0.0f), 1.0f);
    }
    if (lane == 0){ p[idx] = pv; bh[idx] = (pv >= 0.5f) ? 1.0f : 0.0f; }
}

// ---------------- per-batch cumsum via wave scan ----------------
__global__ __launch_bounds__(64) void k_seq(const float* __restrict__ bh, int* __restrict__ cidx,
                      int* __restrict__ dest, int* __restrict__ counts){
    int b = blockIdx.x;
    int lane = threadIdx.x;
    int base = b*L_ + lane*16;
    int h[16];
    int cnt = 0;
    #pragma unroll
    for (int j=0;j<16;j++){ h[j] = bh[base+j] > 0.5f; cnt += h[j]; }
    int inc = cnt;
    #pragma unroll
    for (int o=1;o<64;o<<=1){ int nb = __shfl_up(inc, o); if (lane >= o) inc += nb; }
    int run = inc - cnt;
    #pragma unroll
    for (int j=0;j<16;j++){
        run += h[j];
        int ci = run - 1; if (ci < 0) ci = 0;
        cidx[base+j] = ci;
        dest[base+j] = h[j] ? (run-1) : L_;
    }
    if (lane == 63) counts[b] = inc;
}

__global__ void k_zero(float* p, int n){ int i = blockIdx.x*256+threadIdx.x; if (i < n) p[i] = 0.f; }

__global__ void k_scatter(const float* __restrict__ x, const float* __restrict__ p,
        const int* __restrict__ dest, const float* __restrict__ bh,
        float* __restrict__ comp, float* __restrict__ pcomp)
{
    int i = blockIdx.x;
    int d = threadIdx.x;
    int b = i >> 10;
    if (bh[i] > 0.5f){
        int ds = dest[i];
        comp[((size_t)b*L_ + ds)*DENC + d] = x[(size_t)i*DENC + d];
        if (d == 0) pcomp[b*L_ + ds] = p[i];
    }
}

__global__ __launch_bounds__(256) void k_reduce(const float* __restrict__ p, const float* __restrict__ bh,
                                                float* __restrict__ acc){
    __shared__ float sp[256], sb[256];
    int tid = threadIdx.x;
    float s1=0.f, s2=0.f;
    for (int i = blockIdx.x*256 + tid; i < BL; i += gridDim.x*256){ s1 += p[i]; s2 += bh[i]; }
    sp[tid]=s1; sb[tid]=s2; __syncthreads();
    for (int o=128;o>=1;o>>=1){ if (tid<o){ sp[tid]+=sp[tid+o]; sb[tid]+=sb[tid+o]; } __syncthreads(); }
    if (tid==0){ atomicAdd(&acc[0], sp[0]); atomicAdd(&acc[1], sb[0]); }
}

// ---------------- chunk EMA scan ----------------
__global__ __launch_bounds__(64) void k_ema(const float* __restrict__ z, const float* __restrict__ pcomp,
                                            float* __restrict__ zbar){
    int gid = blockIdx.x*64 + threadIdx.x;
    int b = gid >> 7, d = gid & 127;
    const float* zb = z    + (size_t)b*L_*DENC + d;
    float*       ob = zbar + (size_t)b*L_*DENC + d;
    float prev = 0.f;
    for (int t = 0; t < L_; t++){
        float pc = pcomp[b*L_ + t];
        pc = fminf(fmaxf(pc, 1e-4f), 1.0f-1e-4f);
        float zv = zb[(size_t)t*DENC];
        float a  = (t==0) ? 0.0f : (1.0f - pc);
        float bv = (t==0) ? zv : pc*zv;
        prev = a*prev + bv;
        ob[(size_t)t*DENC] = prev;
    }
}

__global__ void k_combine(float* __restrict__ x, const float* __restrict__ zbar, const int* __restrict__ cidx){
    int i = blockIdx.x*256 + threadIdx.x;
    int row = i >> 7, d = i & 127;
    int b = row >> 10;
    int ci = cidx[row];
    x[i] += zbar[((size_t)b*L_ + ci)*DENC + d];
}

__global__ void k_loss(const float* __restrict__ acc, void* __restrict__ out, const int* __restrict__ flag){
    float G = acc[0] / (float)BL;
    float F = acc[1] / (float)BL;
    float ratio = 1.2f*(5.0f*F*G + (1.0f-F)*(1.0f-G));
    if (flag[0]) ((bf16*)out)[(size_t)BL*VOCAB] = __float2bfloat16(ratio);
    else         ((float*)out)[(size_t)BL*VOCAB] = ratio;
}

// =========================================================================
extern "C" void kernel_launch(void* const* d_in, const int* in_sizes, int n_in,
                              void* d_out, int out_size, void* d_ws, size_t ws_size,
                              hipStream_t stream) {
    (void)out_size; (void)ws_size;
    const int* byte_ids = (const int*)d_in[0];

    float* ws = (float*)d_ws;
    size_t off = 0;
    int* FLAG = (int*)ws; off += 16;
    float* W32 = ws + off;

    k_detect<<<1, 64, 0, stream>>>(d_in[1], FLAG);

    CvtArgs ca;
    const float* w32[32];
    unsigned woff = 0;
    for (int i = 1; i < n_in && i < 32; i++){
        w32[i] = W32 + woff;
        ca.src[i-1] = d_in[i];
        ca.offs[i-1] = woff;
        woff += (unsigned)in_sizes[i];
    }
    ca.offs[31] = woff;
    k_cvt_all<<<2048, 256, 0, stream>>>(ca, W32, (int)woff, FLAG);
    off += woff;

    const float* embed    = w32[1];
    const float* wq       = w32[2];
    const float* wk       = w32[3];
    const float* proj_up  = w32[4];
    const float* proj_dn  = w32[5];
    const float* norm_w   = w32[6];
    const float* norm_b   = w32[7];
    const float* enc_ln1w = w32[8];
    const float* enc_ln1b = w32[9];
    const float* enc_qkv  = w32[10];
    const float* enc_wo   = w32[11];
    const float* enc_ln2w = w32[12];
    const float* enc_ln2b = w32[13];
    const float* enc_w1   = w32[14];
    const float* enc_w2   = w32[15];
    const float* main_ln1w= w32[16];
    const float* main_ln1b= w32[17];
    const float* main_qkv = w32[18];
    const float* main_wo  = w32[19];
    const float* main_ln2w= w32[20];
    const float* main_ln2b= w32[21];
    const float* main_w1  = w32[22];
    const float* main_w2  = w32[23];
    const float* dec_ln1w = w32[24];
    const float* dec_ln1b = w32[25];
    const float* dec_qkv  = w32[26];
    const float* dec_wo   = w32[27];
    const float* dec_ln2w = w32[28];
    const float* dec_ln2b = w32[29];
    const float* dec_w1   = w32[30];
    const float* dec_w2   = w32[31];

    float* X    = ws + off; off += (size_t)BL*DENC;
    float* LN   = ws + off; off += (size_t)BL*DMAIN;
    float* QKV  = ws + off; off += (size_t)BL*3*DMAIN;
    float* ATT  = ws + off; off += (size_t)BL*DMAIN;
    float* H    = ws + off; off += (size_t)BL*2*DMAIN;
    float* Z    = ws + off; off += (size_t)BL*DMAIN;
    float* COMP = ws + off; off += (size_t)BL*DENC;
    float* P    = ws + off; off += BL;
    float* BH   = ws + off; off += BL;
    float* PCOMP= ws + off; off += BL;
    float* ACC  = ws + off; off += 8;
    int* CIDX   = (int*)(ws + off); off += BL;
    int* DEST   = (int*)(ws + off); off += BL;
    int* COUNTS = (int*)(ws + off); off += 64;
    float* TMP  = H;
    float* ZDN  = QKV;
    float* ZBAR = QKV + (size_t)BL*DENC;

    auto gemm32 = [&](const float* A, const float* W, float* C, int N, int K){
        dim3 g((N+GBN-1)/GBN, BL/GBM);
        k_gemm<<<g, 256, 0, stream>>>(A, W, C, BL, N, K);
    };
    auto gemm16 = [&](const float* A, const float* W, const float* R, float* C, void* Ob,
                    int N, int K, int mode){
        dim3 g((N+127)/128, BL/128);
        k_mgemm<<<g, 256, 0, stream>>>(A, W, R, C, Ob, FLAG, BL, N, K, mode,
                                       nullptr, nullptr, nullptr, 0, 0);
    };
    auto gemm_qkv = [&](const float* A, const float* W, int D, int dh){
        int N = 3*D;
        int dS = (D == 128) ? 7 : 8;
        int dhS = (dh == 32) ? 5 : 6;
        float* Qh = QKV;
        float* Kh = QKV + (size_t)BL*D;
        float* Vh = QKV + (size_t)2*BL*D;
        dim3 g((N+127)/128, BL/128);
        k_mgemm<<<g, 256, 0, stream>>>(A, W, nullptr, nullptr, nullptr, FLAG, BL, N, D, 4,
                                       Qh, Kh, Vh, dS, dhS);
    };

    auto block128 = [&](float* Xs, const float* l1w, const float* l1b, const float* qkvw, const float* wo,
                        const float* l2w, const float* l2b, const float* w1, const float* w2){
        k_ln<128><<<BL,64,0,stream>>>(Xs, l1w, l1b, LN);
        gemm_qkv(LN, qkvw, DENC, 32);
        k_flash<32><<<dim3(B_*NHEADS,32),256,0,stream>>>(QKV, QKV+(size_t)BL*DENC, QKV+(size_t)2*BL*DENC,
                                                         ATT, nullptr, 0.17677669529663687f);
        gemm16(ATT, wo, Xs, Xs, nullptr, DENC, DENC, 1);
        k_ln<128><<<BL,64,0,stream>>>(Xs, l2w, l2b, LN);
        gemm16(LN, w1, nullptr, H, nullptr, 2*DENC, DENC, 2);
        gemm16(H, w2, Xs, Xs, nullptr, DENC, 2*DENC, 1);
    };
    auto block256 = [&](float* Xs, const float* l1w, const float* l1b, const float* qkvw, const float* wo,
                        const float* l2w, const float* l2b, const float* w1, const float* w2){
        k_ln<256><<<BL,64,0,stream>>>(Xs, l1w, l1b, LN);
        gemm_qkv(LN, qkvw, DMAIN, 64);
        k_flash<64><<<dim3(B_*NHEADS,32),256,0,stream>>>(QKV, QKV+(size_t)BL*DMAIN, QKV+(size_t)2*BL*DMAIN,
                                                         ATT, COUNTS, 0.125f);
        gemm16(ATT, wo, Xs, Xs, nullptr, DMAIN, DMAIN, 1);
        k_ln<256><<<BL,64,0,stream>>>(Xs, l2w, l2b, LN);
        gemm16(LN, w1, nullptr, H, nullptr, 2*DMAIN, DMAIN, 2);
        gemm16(H, w2, Xs, Xs, nullptr, DMAIN, 2*DMAIN, 1);
    };

    // ---- embed + encoder (MFMA; router-facing wq/wk stay f32) ----
    k_embed<<<BL*DENC/256, 256, 0, stream>>>(byte_ids, embed, X);
    for (int i = 0; i < 3; i++)
        block128(X, enc_ln1w + i*DENC, enc_ln1b + i*DENC, enc_qkv + (size_t)i*3*DENC*DENC,
                 enc_wo + (size_t)i*DENC*DENC, enc_ln2w + i*DENC, enc_ln2b + i*DENC,
                 enc_w1 + (size_t)i*2*DENC*DENC, enc_w2 + (size_t)i*2*DENC*DENC);

    // ---- routing (f32) ----
    gemm32(X, wq, ATT, DENC, DENC);
    gemm32(X, wk, TMP, DENC, DENC);
    k_router<<<BL, 64, 0, stream>>>(ATT, TMP, P, BH);
    k_seq<<<B_, 64, 0, stream>>>(BH, CIDX, DEST, COUNTS);
    k_zero<<<(BL*DENC+255)/256, 256, 0, stream>>>(COMP, BL*DENC);
    k_zero<<<(BL+255)/256, 256, 0, stream>>>(PCOMP, BL);
    k_zero<<<1, 256, 0, stream>>>(ACC, 8);
    k_scatter<<<BL, 128, 0, stream>>>(X, P, DEST, BH, COMP, PCOMP);
    k_reduce<<<8, 256, 0, stream>>>(P, BH, ACC);

    // ---- main stack on compressed (f16 MFMA) ----
    gemm16(COMP, proj_up, nullptr, Z, nullptr, DMAIN, DENC, 0);
    for (int i = 0; i < 6; i++)
        block256(Z, main_ln1w + i*DMAIN, main_ln1b + i*DMAIN, main_qkv + (size_t)i*3*DMAIN*DMAIN,
                 main_wo + (size_t)i*DMAIN*DMAIN, main_ln2w + i*DMAIN, main_ln2b + i*DMAIN,
                 main_w1 + (size_t)i*2*DMAIN*DMAIN, main_w2 + (size_t)i*2*DMAIN*DMAIN);
    gemm16(Z, proj_dn, nullptr, ZDN, nullptr, DENC, DMAIN, 0);

    // ---- EMA + dechunk combine ----
    k_ema<<<B_*DENC/64, 64, 0, stream>>>(ZDN, PCOMP, ZBAR);
    k_combine<<<BL*DENC/256, 256, 0, stream>>>(X, ZBAR, CIDX);

    // ---- decoder (f16 MFMA) ----
    for (int i = 0; i < 3; i++)
        block128(X, dec_ln1w + i*DENC, dec_ln1b + i*DENC, dec_qkv + (size_t)i*3*DENC*DENC,
                 dec_wo + (size_t)i*DENC*DENC, dec_ln2w + i*DENC, dec_ln2b + i*DENC,
                 dec_w1 + (size_t)i*2*DENC*DENC, dec_w2 + (size_t)i*2*DENC*DENC);

    // ---- final LN + tied head + loss ----
    k_ln<128><<<BL,64,0,stream>>>(X, norm_w, norm_b, LN);
    gemm16(LN, embed, nullptr, nullptr, d_out, VOCAB, DENC, 3);
    k_loss<<<1,1,0,stream>>>(ACC, d_out, FLAG);
}

// Round 6
// 2121.597 us; speedup vs baseline: 2.6441x; 1.0957x over previous
//
#include <hip/hip_runtime.h>
#include <hip/hip_bf16.h>

#define B_ 8
#define L_ 1024
#define BL (B_*L_)
#define DENC 128
#define DMAIN 256
#define VOCAB 260
#define NHEADS 4

typedef __hip_bfloat16 bf16;
typedef _Float16 f16;
typedef f16 half8 __attribute__((ext_vector_type(8)));
typedef float f32x4 __attribute__((ext_vector_type(4)));

// ---------------- dtype detector ----------------
__global__ __launch_bounds__(64) void k_detect(const void* __restrict__ emb, int* __restrict__ flag){
    int lane = threadIdx.x;
    const unsigned short* u = (const unsigned short*)emb;
    int bad = 0;
    #pragma unroll
    for (int j = 0; j < 4; j++){
        unsigned short h = u[lane + 64*j];
        bf16 t = *(const bf16*)&h;
        float v = __bfloat162float(t);
        if (!(fabsf(v) < 1e4f)) bad++;
    }
    #pragma unroll
    for (int o = 32; o >= 1; o >>= 1) bad += __shfl_xor(bad, o);
    if (lane == 0) flag[0] = (bad == 0) ? 1 : 0;
}

// ---------------- fused convert of all 31 float inputs ----------------
struct CvtArgs {
    const void* src[31];
    unsigned offs[32];
};
__global__ void k_cvt_all(CvtArgs a, float* __restrict__ dst, int total, const int* __restrict__ flag){
    int isbf = flag[0];
    for (int i = blockIdx.x*256 + threadIdx.x; i < total; i += gridDim.x*256){
        int lo = 0, hi = 30;
        while (lo < hi){ int mid = (lo+hi+1)>>1; if (a.offs[mid] <= (unsigned)i) lo = mid; else hi = mid-1; }
        int j = i - (int)a.offs[lo];
        dst[i] = isbf ? __bfloat162float(((const bf16*)a.src[lo])[j])
                      : ((const float*)a.src[lo])[j];
    }
}

// ---------------- embed gather ----------------
__global__ void k_embed(const int* __restrict__ ids, const float* __restrict__ emb, float* __restrict__ x){
    int i = blockIdx.x*256 + threadIdx.x;
    int row = i >> 7, d = i & 127;
    x[i] = emb[ids[row]*DENC + d];
}

// ---------------- layernorm (one wave per row) ----------------
template<int D>
__global__ __launch_bounds__(64) void k_ln(const float* __restrict__ x, const float* __restrict__ w,
                                           const float* __restrict__ b, float* __restrict__ y){
    int row = blockIdx.x;
    int lane = threadIdx.x;
    const float* xr = x + (size_t)row*D;
    float v[D/64];
    float s = 0.f;
    #pragma unroll
    for (int j=0;j<D/64;j++){ v[j] = xr[lane + j*64]; s += v[j]; }
    #pragma unroll
    for (int o=32;o>=1;o>>=1) s += __shfl_xor(s,o);
    float mu = s / (float)D;
    float s2 = 0.f;
    #pragma unroll
    for (int j=0;j<D/64;j++){ float dd = v[j]-mu; s2 += dd*dd; }
    #pragma unroll
    for (int o=32;o>=1;o>>=1) s2 += __shfl_xor(s2,o);
    float inv = rsqrtf(s2/(float)D + 1e-5f);
    float* yr = y + (size_t)row*D;
    #pragma unroll
    for (int j=0;j<D/64;j++){
        int d = lane + j*64;
        yr[d] = (v[j]-mu)*inv*w[d] + b[d];
    }
}

// ---------------- f32 vector GEMM (router wq/wk only) ----------------
#define GBM 64
#define GBN 64
#define GBK 32
__global__ __launch_bounds__(256) void k_gemm(const float* __restrict__ A, const float* __restrict__ W,
        float* __restrict__ C, int M, int N, int K)
{
    __shared__ float As[GBK][GBM+4];
    __shared__ float Ws[GBK][GBN+4];
    int tid = threadIdx.x;
    int bm = blockIdx.y * GBM;
    int bn = blockIdx.x * GBN;
    int tx = tid & 15, ty = tid >> 4;
    float acc[4][4] = {};
    for (int k0 = 0; k0 < K; k0 += GBK){
        #pragma unroll
        for (int i = tid; i < GBM*GBK; i += 256){
            int m = i >> 5, kk = i & 31;
            As[kk][m] = A[(size_t)(bm+m)*K + k0 + kk];
        }
        #pragma unroll
        for (int i = tid; i < GBN*GBK; i += 256){
            int n = i >> 5, kk = i & 31;
            int gn = bn + n;
            Ws[kk][n] = (gn < N) ? W[(size_t)gn*K + k0 + kk] : 0.0f;
        }
        __syncthreads();
        #pragma unroll
        for (int kk = 0; kk < GBK; kk++){
            float a0[4], w0[4];
            *(float4*)a0 = *(const float4*)&As[kk][ty*4];
            *(float4*)w0 = *(const float4*)&Ws[kk][tx*4];
            #pragma unroll
            for (int i=0;i<4;i++)
                #pragma unroll
                for (int j=0;j<4;j++) acc[i][j] += a0[i]*w0[j];
        }
        __syncthreads();
    }
    #pragma unroll
    for (int i=0;i<4;i++){
        int m = bm + ty*4 + i;
        #pragma unroll
        for (int j=0;j<4;j++){
            int n = bn + tx*4 + j;
            if (n < N) C[(size_t)m*N + n] = acc[i][j];
        }
    }
}

// ---------------- f16 MFMA GEMM ----------------
// modes: 0 plain, 1 +R, 2 gelu, 3 out-store, 4 split-head QKV f32, 5 split-head QKV f16 (V transposed)
__global__ __launch_bounds__(256) void k_mgemm(const float* __restrict__ A, const float* __restrict__ W,
        const float* __restrict__ R, float* __restrict__ C, void* __restrict__ OutRaw,
        const int* __restrict__ flag, int M, int N, int K, int mode,
        float* __restrict__ Qd, float* __restrict__ Kd, float* __restrict__ Vd,
        int dShift, int dhShift)
{
    __shared__ half8 As[4][128];
    __shared__ half8 Ws[4][128];
    int tid = threadIdx.x;
    int wave = tid >> 6, lane = tid & 63;
    int wr = wave >> 1, wc = wave & 1;
    int quad = lane >> 4, l15 = lane & 15;
    int bm = blockIdx.y * 128;
    int bn = blockIdx.x * 128;

    f32x4 acc[4][4] = {};

    int srow = tid >> 1;
    int skc = (tid & 1) * 2;
    const float* ap0 = A + (size_t)(bm + srow)*K + skc*8;
    int gn = bn + srow;
    const float* wp0 = W + (size_t)gn*K + skc*8;
    bool wok = (gn < N);

    for (int k0 = 0; k0 < K; k0 += 32){
        __syncthreads();
        {
            const float* ap = ap0 + k0;
            float4 u0 = *(const float4*)(ap);
            float4 u1 = *(const float4*)(ap+4);
            float4 u2 = *(const float4*)(ap+8);
            float4 u3 = *(const float4*)(ap+12);
            half8 h0, h1;
            h0[0]=(f16)u0.x; h0[1]=(f16)u0.y; h0[2]=(f16)u0.z; h0[3]=(f16)u0.w;
            h0[4]=(f16)u1.x; h0[5]=(f16)u1.y; h0[6]=(f16)u1.z; h0[7]=(f16)u1.w;
            h1[0]=(f16)u2.x; h1[1]=(f16)u2.y; h1[2]=(f16)u2.z; h1[3]=(f16)u2.w;
            h1[4]=(f16)u3.x; h1[5]=(f16)u3.y; h1[6]=(f16)u3.z; h1[7]=(f16)u3.w;
            As[skc][srow] = h0;
            As[skc+1][srow] = h1;
            half8 g0 = (half8)(f16)0.f, g1 = (half8)(f16)0.f;
            if (wok){
                const float* wp = wp0 + k0;
                float4 v0 = *(const float4*)(wp);
                float4 v1 = *(const float4*)(wp+4);
                float4 v2 = *(const float4*)(wp+8);
                float4 v3 = *(const float4*)(wp+12);
                g0[0]=(f16)v0.x; g0[1]=(f16)v0.y; g0[2]=(f16)v0.z; g0[3]=(f16)v0.w;
                g0[4]=(f16)v1.x; g0[5]=(f16)v1.y; g0[6]=(f16)v1.z; g0[7]=(f16)v1.w;
                g1[0]=(f16)v2.x; g1[1]=(f16)v2.y; g1[2]=(f16)v2.z; g1[3]=(f16)v2.w;
                g1[4]=(f16)v3.x; g1[5]=(f16)v3.y; g1[6]=(f16)v3.z; g1[7]=(f16)v3.w;
            }
            Ws[skc][srow] = g0;
            Ws[skc+1][srow] = g1;
        }
        __syncthreads();

        half8 af[4], wf[4];
        #pragma unroll
        for (int i=0;i<4;i++) af[i] = As[quad][wr*64 + i*16 + l15];
        #pragma unroll
        for (int j=0;j<4;j++) wf[j] = Ws[quad][wc*64 + j*16 + l15];
        #pragma unroll
        for (int i=0;i<4;i++)
            #pragma unroll
            for (int j=0;j<4;j++)
                acc[i][j] = __builtin_amdgcn_mfma_f32_16x16x32_f16(af[i], wf[j], acc[i][j], 0, 0, 0);
    }

    #pragma unroll
    for (int j=0;j<4;j++){
        int n = bn + wc*64 + j*16 + l15;
        if (n >= N) continue;
        #pragma unroll
        for (int i=0;i<4;i++){
            #pragma unroll
            for (int r=0;r<4;r++){
                int m = bm + wr*64 + i*16 + quad*4 + r;
                float v = acc[i][j][r];
                if (mode >= 4){
                    int which = n >> dShift;
                    int rem = n & ((1<<dShift)-1);
                    int hh = rem >> dhShift;
                    int dd = rem & ((1<<dhShift)-1);
                    int bb = m >> 10, tt = m & 1023;
                    int Hn = 1 << (dShift - dhShift);
                    if (mode == 4){
                        float* dst = (which==0) ? Qd : ((which==1) ? Kd : Vd);
                        dst[((((size_t)bb*Hn + hh)*L_ + tt) << dhShift) + dd] = v;
                    } else {
                        f16* dst = (which==0) ? (f16*)Qd : ((which==1) ? (f16*)Kd : (f16*)Vd);
                        if (which == 2)
                            dst[((((size_t)bb*Hn + hh) << dhShift) + dd)*L_ + tt] = (f16)v;  // V^T
                        else
                            dst[((((size_t)bb*Hn + hh)*L_ + tt) << dhShift) + dd] = (f16)v;
                    }
                    continue;
                }
                size_t off = (size_t)m*N + n;
                if (mode == 1) v += R[off];
                else if (mode == 2) v = 0.5f*v*(1.0f + erff(v*0.70710678118654752f));
                if (mode == 3){
                    if (flag[0]) ((bf16*)OutRaw)[off] = __float2bfloat16(v);
                    else         ((float*)OutRaw)[off] = v;
                } else C[off] = v;
            }
        }
    }
}

// ---------------- f32 flash (encoder only; router-sensitive) ----------------
template<int DH>
__global__ __launch_bounds__(256) void k_flash(const float* __restrict__ Qh, const float* __restrict__ Kh,
        const float* __restrict__ Vh, float* __restrict__ out, const int* __restrict__ counts,
        float scale)
{
    constexpr int BQ = 32, BK = 64;
    constexpr int QS = 36;
    constexpr int KS = 68;
    __shared__ float sQt[DH*QS];
    __shared__ float sKtP[(DH>32?DH:32)*KS];
    __shared__ float sV [BK*DH];

    int x = blockIdx.x;
    int b = x >> 2, h = x & 3;
    int yy = blockIdx.y;
    int qt = (yy < 16) ? yy : 47 - yy;
    int q0 = qt * BQ;

    int tid = threadIdx.x;
    int tx = tid & 15, ty = tid >> 4;

    const float* Qb = Qh + ((size_t)x*L_)*DH;
    const float* Kb = Kh + ((size_t)x*L_)*DH;
    const float* Vb = Vh + ((size_t)x*L_)*DH;

    int kcap = counts ? counts[b] : L_;
    int klen = min(kcap, q0 + BQ);

    {
        const float4* src = (const float4*)(Qb + (size_t)q0*DH);
        for (int i = tid; i < BQ*DH/4; i += 256){
            float4 v = src[i];
            int t = (4*i) / DH, d = (4*i) % DH;
            sQt[(d+0)*QS + t] = v.x;
            sQt[(d+1)*QS + t] = v.y;
            sQt[(d+2)*QS + t] = v.z;
            sQt[(d+3)*QS + t] = v.w;
        }
    }

    float m[2] = {-1e30f,-1e30f}, l[2] = {0.f,0.f};
    float o[2][4] = {};
    int q[2] = {q0 + 2*ty, q0 + 2*ty + 1};

    for (int k0 = 0; k0 < klen; k0 += BK){
        __syncthreads();
        {
            const float4* ks = (const float4*)(Kb + (size_t)k0*DH);
            const float4* vs = (const float4*)(Vb + (size_t)k0*DH);
            for (int i = tid; i < BK*DH/4; i += 256){
                float4 kv = ks[i];
                int t = (4*i) / DH, d = (4*i) % DH;
                sKtP[(d+0)*KS + t] = kv.x;
                sKtP[(d+1)*KS + t] = kv.y;
                sKtP[(d+2)*KS + t] = kv.z;
                sKtP[(d+3)*KS + t] = kv.w;
                ((float4*)sV)[i] = vs[i];
            }
        }
        __syncthreads();

        float s[2][4] = {};
        #pragma unroll 4
        for (int d = 0; d < DH; d++){
            float2 qv = *(const float2*)&sQt[d*QS + 2*ty];
            float4 kv = *(const float4*)&sKtP[d*KS + 4*tx];
            s[0][0] += qv.x*kv.x; s[0][1] += qv.x*kv.y; s[0][2] += qv.x*kv.z; s[0][3] += qv.x*kv.w;
            s[1][0] += qv.y*kv.x; s[1][1] += qv.y*kv.y; s[1][2] += qv.y*kv.z; s[1][3] += qv.y*kv.w;
        }
        float4 pr[2];
        #pragma unroll
        for (int i=0;i<2;i++){
            #pragma unroll
            for (int j=0;j<4;j++){
                float v = s[i][j]*scale;
                int k = k0 + tx*4 + j;
                if (k > q[i] || k >= kcap) v = -1e30f;
                s[i][j] = v;
            }
            float rm = fmaxf(fmaxf(s[i][0],s[i][1]), fmaxf(s[i][2],s[i][3]));
            rm = fmaxf(rm, __shfl_xor(rm, 1));
            rm = fmaxf(rm, __shfl_xor(rm, 2));
            rm = fmaxf(rm, __shfl_xor(rm, 4));
            rm = fmaxf(rm, __shfl_xor(rm, 8));
            float mn = fmaxf(m[i], rm);
            float al = __expf(m[i] - mn);
            float p0 = __expf(s[i][0]-mn), p1 = __expf(s[i][1]-mn);
            float p2 = __expf(s[i][2]-mn), p3 = __expf(s[i][3]-mn);
            float rs = p0+p1+p2+p3;
            rs += __shfl_xor(rs, 1);
            rs += __shfl_xor(rs, 2);
            rs += __shfl_xor(rs, 4);
            rs += __shfl_xor(rs, 8);
            l[i] = l[i]*al + rs;
            m[i] = mn;
            o[i][0]*=al; o[i][1]*=al; o[i][2]*=al; o[i][3]*=al;
            pr[i] = make_float4(p0,p1,p2,p3);
        }
        __syncthreads();
        *(float4*)&sKtP[(2*ty+0)*KS + 4*tx] = pr[0];
        *(float4*)&sKtP[(2*ty+1)*KS + 4*tx] = pr[1];
        __syncthreads();

        if (4*tx < DH){
            #pragma unroll 2
            for (int kc = 0; kc < BK; kc += 4){
                float4 p0 = *(const float4*)&sKtP[(2*ty+0)*KS + kc];
                float4 p1 = *(const float4*)&sKtP[(2*ty+1)*KS + kc];
                float pa0[4] = {p0.x,p0.y,p0.z,p0.w};
                float pa1[4] = {p1.x,p1.y,p1.z,p1.w};
                #pragma unroll
                for (int jk=0;jk<4;jk++){
                    float4 vv = *(const float4*)&sV[(kc+jk)*DH + 4*tx];
                    o[0][0] += pa0[jk]*vv.x; o[0][1] += pa0[jk]*vv.y;
                    o[0][2] += pa0[jk]*vv.z; o[0][3] += pa0[jk]*vv.w;
                    o[1][0] += pa1[jk]*vv.x; o[1][1] += pa1[jk]*vv.y;
                    o[1][2] += pa1[jk]*vv.z; o[1][3] += pa1[jk]*vv.w;
                }
            }
        }
    }

    if (4*tx < DH){
        #pragma unroll
        for (int i=0;i<2;i++){
            float inv = 1.0f / l[i];
            float4 r = make_float4(o[i][0]*inv, o[i][1]*inv, o[i][2]*inv, o[i][3]*inv);
            *(float4*)&out[((size_t)b*L_ + q[i])*(4*DH) + h*DH + 4*tx] = r;
        }
    }
}

// ---------------- MFMA f16 flash (main + decoder) ----------------
// block = 4 waves, BQ=64 (wave w owns q rows 16w..16w+15), BK=64
template<int DH>
__global__ __launch_bounds__(256) void k_mflash(const f16* __restrict__ Qh, const f16* __restrict__ Kh,
        const f16* __restrict__ Vt, float* __restrict__ out, const int* __restrict__ counts,
        float scale)
{
    constexpr int BQ = 64, BK = 64;
    constexpr int RS = DH + 8;     // Q/K row stride (halves), 16B-aligned
    constexpr int PS = BK + 8;     // P/Vt row stride (halves)
    __shared__ f16 sQ[BQ*RS];
    __shared__ f16 sK[BK*RS];
    __shared__ f16 sVt[DH*PS];
    __shared__ f16 sP[BQ*PS];

    int x = blockIdx.x, b = x >> 2, h = x & 3;
    int yy = blockIdx.y;
    int qt = (yy < 8) ? yy : 23 - yy;
    int q0 = qt * BQ;
    int tid = threadIdx.x;
    int wv = tid >> 6, lane = tid & 63;
    int quad = lane >> 4, l15 = lane & 15;

    const f16* Qb = Qh + (size_t)x*L_*DH;
    const f16* Kb = Kh + (size_t)x*L_*DH;
    const f16* Vb = Vt + (size_t)x*DH*L_;
    int kcap = counts ? counts[b] : L_;
    int klen = min(kcap, q0 + BQ);

    // stage Q rows
    for (int i = tid; i < BQ*DH/8; i += 256){
        int r = (8*i)/DH, c = (8*i)%DH;
        *(half8*)&sQ[r*RS + c] = *(const half8*)&Qb[(size_t)(q0+r)*DH + c];
    }

    float m[4], l[4];
    #pragma unroll
    for (int r=0;r<4;r++){ m[r] = -1e30f; l[r] = 0.f; }
    f32x4 accO[DH/16] = {};

    for (int k0 = 0; k0 < klen; k0 += BK){
        __syncthreads();
        for (int i = tid; i < BK*DH/8; i += 256){
            int r = (8*i)/DH, c = (8*i)%DH;
            *(half8*)&sK[r*RS + c] = *(const half8*)&Kb[(size_t)(k0+r)*DH + c];
        }
        for (int i = tid; i < DH*BK/8; i += 256){
            int r = (8*i)/BK, c = (8*i)%BK;
            *(half8*)&sVt[r*PS + c] = *(const half8*)&Vb[(size_t)r*L_ + k0 + c];
        }
        __syncthreads();

        // ---- S = Q K^T ----
        half8 af[DH/32];
        #pragma unroll
        for (int ds=0; ds<DH/32; ds++)
            af[ds] = *(const half8*)&sQ[(16*wv + l15)*RS + quad*8 + 32*ds];
        f32x4 accS[4] = {};
        #pragma unroll
        for (int t=0;t<4;t++){
            #pragma unroll
            for (int ds=0; ds<DH/32; ds++){
                half8 bf = *(const half8*)&sK[(16*t + l15)*RS + quad*8 + 32*ds];
                accS[t] = __builtin_amdgcn_mfma_f32_16x16x32_f16(af[ds], bf, accS[t], 0, 0, 0);
            }
        }

        // ---- mask + online softmax (C layout: row=quad*4+r, col=16t+l15) ----
        #pragma unroll
        for (int r=0;r<4;r++){
            int qrow = q0 + 16*wv + quad*4 + r;
            float sv[4];
            #pragma unroll
            for (int t=0;t<4;t++){
                float v = accS[t][r]*scale;
                int kp = k0 + 16*t + l15;
                if (kp > qrow || kp >= kcap) v = -1e30f;
                sv[t] = v;
            }
            float rm = fmaxf(fmaxf(sv[0],sv[1]), fmaxf(sv[2],sv[3]));
            rm = fmaxf(rm, __shfl_xor(rm, 1));
            rm = fmaxf(rm, __shfl_xor(rm, 2));
            rm = fmaxf(rm, __shfl_xor(rm, 4));
            rm = fmaxf(rm, __shfl_xor(rm, 8));
            float mn = fmaxf(m[r], rm);
            float al = __expf(m[r] - mn);
            float p0 = __expf(sv[0]-mn), p1 = __expf(sv[1]-mn);
            float p2 = __expf(sv[2]-mn), p3 = __expf(sv[3]-mn);
            float rs = p0+p1+p2+p3;
            rs += __shfl_xor(rs, 1);
            rs += __shfl_xor(rs, 2);
            rs += __shfl_xor(rs, 4);
            rs += __shfl_xor(rs, 8);
            l[r] = l[r]*al + rs;
            m[r] = mn;
            #pragma unroll
            for (int dt=0; dt<DH/16; dt++) accO[dt][r] *= al;
            int prow = 16*wv + quad*4 + r;
            sP[prow*PS + 16*0 + l15] = (f16)p0;
            sP[prow*PS + 16*1 + l15] = (f16)p1;
            sP[prow*PS + 16*2 + l15] = (f16)p2;
            sP[prow*PS + 16*3 + l15] = (f16)p3;
        }

        // ---- O += P V (wave-local band of sP; compiler orders LDS deps) ----
        half8 pf[2];
        #pragma unroll
        for (int ks=0; ks<2; ks++)
            pf[ks] = *(const half8*)&sP[(16*wv + l15)*PS + quad*8 + 32*ks];
        #pragma unroll
        for (int dt=0; dt<DH/16; dt++){
            #pragma unroll
            for (int ks=0; ks<2; ks++){
                half8 bv = *(const half8*)&sVt[(16*dt + l15)*PS + quad*8 + 32*ks];
                accO[dt] = __builtin_amdgcn_mfma_f32_16x16x32_f16(pf[ks], bv, accO[dt], 0, 0, 0);
            }
        }
    }

    // ---- epilogue ----
    #pragma unroll
    for (int r=0;r<4;r++){
        float inv = 1.0f / l[r];
        int qrow = q0 + 16*wv + quad*4 + r;
        #pragma unroll
        for (int dt=0; dt<DH/16; dt++){
            int d = 16*dt + l15;
            out[((size_t)b*L_ + qrow)*(NHEADS*DH) + h*DH + d] = accO[dt][r]*inv;
        }
    }
}

// ---------------- router ----------------
__global__ __launch_bounds__(64) void k_router(const float* __restrict__ Q, const float* __restrict__ Kr,
        float* __restrict__ p, float* __restrict__ bh)
{
    int idx = blockIdx.x;
    int t = idx & (L_-1);
    int lane = threadIdx.x;
    float pv;
    if (t == 0){ pv = 1.0f; }
    else {
        const float* qr = Q  + (size_t)idx*DENC;
        const float* kr = Kr + (size_t)(idx-1)*DENC;
        float qq=0.f, kk=0.f, qk=0.f;
        #pragma unroll
        for (int j=0;j<2;j++){
            float qv = qr[lane + j*64], kv = kr[lane + j*64];
            qq += qv*qv; kk += kv*kv; qk += qv*kv;
        }
        #pragma unroll
        for (int o=32;o>=1;o>>=1){ qq += __shfl_xor(qq,o); kk += __shfl_xor(kk,o); qk += __shfl_xor(qk,o); }
        float cosv = qk / (fmaxf(sqrtf(qq),1e-12f)*fmaxf(sqrtf(kk),1e-12f));
        pv = 0.5f*(1.0f - cosv);
        pv = fminf(fmaxf(pv, 0.0f), 1.0f);
    }
    if (lane == 0){ p[idx] = pv; bh[idx] = (pv >= 0.5f) ? 1.0f : 0.0f; }
}

// ---------------- per-batch cumsum via wave scan ----------------
__global__ __launch_bounds__(64) void k_seq(const float* __restrict__ bh, int* __restrict__ cidx,
                      int* __restrict__ dest, int* __restrict__ counts){
    int b = blockIdx.x;
    int lane = threadIdx.x;
    int base = b*L_ + lane*16;
    int h[16];
    int cnt = 0;
    #pragma unroll
    for (int j=0;j<16;j++){ h[j] = bh[base+j] > 0.5f; cnt += h[j]; }
    int inc = cnt;
    #pragma unroll
    for (int o=1;o<64;o<<=1){ int nb = __shfl_up(inc, o); if (lane >= o) inc += nb; }
    int run = inc - cnt;
    #pragma unroll
    for (int j=0;j<16;j++){
        run += h[j];
        int ci = run - 1; if (ci < 0) ci = 0;
        cidx[base+j] = ci;
        dest[base+j] = h[j] ? (run-1) : L_;
    }
    if (lane == 63) counts[b] = inc;
}

__global__ void k_zeroinit(float* __restrict__ comp, float* __restrict__ pcomp, float* __restrict__ acc){
    int i = blockIdx.x*256 + threadIdx.x;
    comp[i] = 0.f;                    // grid exactly BL*DENC/256
    if (i < BL) pcomp[i] = 0.f;
    if (i < 8) acc[i] = 0.f;
}

__global__ void k_scatter(const float* __restrict__ x, const float* __restrict__ p,
        const int* __restrict__ dest, const float* __restrict__ bh,
        float* __restrict__ comp, float* __restrict__ pcomp)
{
    int i = blockIdx.x;
    int d = threadIdx.x;
    int b = i >> 10;
    if (bh[i] > 0.5f){
        int ds = dest[i];
        comp[((size_t)b*L_ + ds)*DENC + d] = x[(size_t)i*DENC + d];
        if (d == 0) pcomp[b*L_ + ds] = p[i];
    }
}

__global__ __launch_bounds__(256) void k_reduce(const float* __restrict__ p, const float* __restrict__ bh,
                                                float* __restrict__ acc){
    __shared__ float sp[256], sb[256];
    int tid = threadIdx.x;
    float s1=0.f, s2=0.f;
    for (int i = blockIdx.x*256 + tid; i < BL; i += gridDim.x*256){ s1 += p[i]; s2 += bh[i]; }
    sp[tid]=s1; sb[tid]=s2; __syncthreads();
    for (int o=128;o>=1;o>>=1){ if (tid<o){ sp[tid]+=sp[tid+o]; sb[tid]+=sb[tid+o]; } __syncthreads(); }
    if (tid==0){ atomicAdd(&acc[0], sp[0]); atomicAdd(&acc[1], sb[0]); }
}

// ---------------- chunk EMA: 3-phase wave scan, wave per (b,d) ----------------
__global__ __launch_bounds__(256) void k_ema2(const float* __restrict__ z, const float* __restrict__ pcomp,
                                              float* __restrict__ zbar){
    __shared__ float sp[L_];
    int blk = blockIdx.x;              // 256 blocks; 4 waves = 4 consecutive d, same b
    int b = blk >> 5;
    int tid = threadIdx.x, wv = tid >> 6, lane = tid & 63;
    int d = ((blk & 31) << 2) + wv;
    for (int i = tid; i < L_; i += 256){
        float pc = pcomp[b*L_ + i];
        sp[i] = fminf(fmaxf(pc, 1e-4f), 1.0f - 1e-4f);
    }
    __syncthreads();
    const float* zb = z + ((size_t)b*L_)*DENC + d;
    int t0 = lane*16;
    float zv[16];
    #pragma unroll
    for (int i=0;i<16;i++) zv[i] = zb[(size_t)(t0+i)*DENC];
    float A = 1.f, Bv = 0.f;
    #pragma unroll
    for (int i=0;i<16;i++){
        int t = t0 + i;
        float pc = sp[t];
        float a  = (t==0) ? 0.f : (1.f - pc);
        float bb = (t==0) ? zv[i] : pc*zv[i];
        A = a*A;
        Bv = a*Bv + bb;
    }
    #pragma unroll
    for (int off=1; off<64; off<<=1){
        float Ap = __shfl_up(A, off);
        float Bp = __shfl_up(Bv, off);
        if (lane >= off){ Bv = A*Bp + Bv; A = A*Ap; }
    }
    float sin_ = __shfl_up(Bv, 1);
    if (lane == 0) sin_ = 0.f;
    float s = sin_;
    float* ob = zbar + ((size_t)b*L_)*DENC + d;
    #pragma unroll
    for (int i=0;i<16;i++){
        int t = t0 + i;
        float pc = sp[t];
        float a  = (t==0) ? 0.f : (1.f - pc);
        float bb = (t==0) ? zv[i] : pc*zv[i];
        s = a*s + bb;
        ob[(size_t)t*DENC] = s;
    }
}

__global__ void k_combine(float* __restrict__ x, const float* __restrict__ zbar, const int* __restrict__ cidx){
    int i = blockIdx.x*256 + threadIdx.x;
    int row = i >> 7, d = i & 127;
    int b = row >> 10;
    int ci = cidx[row];
    x[i] += zbar[((size_t)b*L_ + ci)*DENC + d];
}

__global__ void k_loss(const float* __restrict__ acc, void* __restrict__ out, const int* __restrict__ flag){
    float G = acc[0] / (float)BL;
    float F = acc[1] / (float)BL;
    float ratio = 1.2f*(5.0f*F*G + (1.0f-F)*(1.0f-G));
    if (flag[0]) ((bf16*)out)[(size_t)BL*VOCAB] = __float2bfloat16(ratio);
    else         ((float*)out)[(size_t)BL*VOCAB] = ratio;
}

// =========================================================================
extern "C" void kernel_launch(void* const* d_in, const int* in_sizes, int n_in,
                              void* d_out, int out_size, void* d_ws, size_t ws_size,
                              hipStream_t stream) {
    (void)out_size; (void)ws_size;
    const int* byte_ids = (const int*)d_in[0];

    float* ws = (float*)d_ws;
    size_t off = 0;
    int* FLAG = (int*)ws; off += 16;
    float* W32 = ws + off;

    k_detect<<<1, 64, 0, stream>>>(d_in[1], FLAG);

    CvtArgs ca;
    const float* w32[32];
    unsigned woff = 0;
    for (int i = 1; i < n_in && i < 32; i++){
        w32[i] = W32 + woff;
        ca.src[i-1] = d_in[i];
        ca.offs[i-1] = woff;
        woff += (unsigned)in_sizes[i];
    }
    ca.offs[31] = woff;
    k_cvt_all<<<2048, 256, 0, stream>>>(ca, W32, (int)woff, FLAG);
    off += woff;

    const float* embed    = w32[1];
    const float* wq       = w32[2];
    const float* wk       = w32[3];
    const float* proj_up  = w32[4];
    const float* proj_dn  = w32[5];
    const float* norm_w   = w32[6];
    const float* norm_b   = w32[7];
    const float* enc_ln1w = w32[8];
    const float* enc_ln1b = w32[9];
    const float* enc_qkv  = w32[10];
    const float* enc_wo   = w32[11];
    const float* enc_ln2w = w32[12];
    const float* enc_ln2b = w32[13];
    const float* enc_w1   = w32[14];
    const float* enc_w2   = w32[15];
    const float* main_ln1w= w32[16];
    const float* main_ln1b= w32[17];
    const float* main_qkv = w32[18];
    const float* main_wo  = w32[19];
    const float* main_ln2w= w32[20];
    const float* main_ln2b= w32[21];
    const float* main_w1  = w32[22];
    const float* main_w2  = w32[23];
    const float* dec_ln1w = w32[24];
    const float* dec_ln1b = w32[25];
    const float* dec_qkv  = w32[26];
    const float* dec_wo   = w32[27];
    const float* dec_ln2w = w32[28];
    const float* dec_ln2b = w32[29];
    const float* dec_w1   = w32[30];
    const float* dec_w2   = w32[31];

    float* X    = ws + off; off += (size_t)BL*DENC;
    float* LN   = ws + off; off += (size_t)BL*DMAIN;
    float* QKV  = ws + off; off += (size_t)BL*3*DMAIN;
    float* ATT  = ws + off; off += (size_t)BL*DMAIN;
    float* H    = ws + off; off += (size_t)BL*2*DMAIN;
    float* Z    = ws + off; off += (size_t)BL*DMAIN;
    float* COMP = ws + off; off += (size_t)BL*DENC;
    float* P    = ws + off; off += BL;
    float* BH   = ws + off; off += BL;
    float* PCOMP= ws + off; off += BL;
    float* ACC  = ws + off; off += 8;
    int* CIDX   = (int*)(ws + off); off += BL;
    int* DEST   = (int*)(ws + off); off += BL;
    int* COUNTS = (int*)(ws + off); off += 64;
    float* TMP  = H;
    float* ZDN  = QKV;
    float* ZBAR = QKV + (size_t)BL*DENC;

    auto gemm32 = [&](const float* A, const float* W, float* C, int N, int K){
        dim3 g((N+GBN-1)/GBN, BL/GBM);
        k_gemm<<<g, 256, 0, stream>>>(A, W, C, BL, N, K);
    };
    auto gemm16 = [&](const float* A, const float* W, const float* R, float* C, void* Ob,
                    int N, int K, int mode){
        dim3 g((N+127)/128, BL/128);
        k_mgemm<<<g, 256, 0, stream>>>(A, W, R, C, Ob, FLAG, BL, N, K, mode,
                                       nullptr, nullptr, nullptr, 0, 0);
    };
    auto gemm_qkv = [&](const float* A, const float* W, int D, int dh, int mode){
        int N = 3*D;
        int dS = (D == 128) ? 7 : 8;
        int dhS = (dh == 32) ? 5 : 6;
        float* Qh = QKV;
        float* Kh = (float*)((char*)QKV + (size_t)BL*D*((mode==5)?2:4));
        float* Vh = (float*)((char*)QKV + (size_t)2*BL*D*((mode==5)?2:4));
        dim3 g((N+127)/128, BL/128);
        k_mgemm<<<g, 256, 0, stream>>>(A, W, nullptr, nullptr, nullptr, FLAG, BL, N, D, mode,
                                       Qh, Kh, Vh, dS, dhS);
    };

    // encoder block: f32 flash (router-sensitive)
    auto block_enc = [&](float* Xs, const float* l1w, const float* l1b, const float* qkvw, const float* wo,
                        const float* l2w, const float* l2b, const float* w1, const float* w2){
        k_ln<128><<<BL,64,0,stream>>>(Xs, l1w, l1b, LN);
        gemm_qkv(LN, qkvw, DENC, 32, 4);
        k_flash<32><<<dim3(B_*NHEADS,32),256,0,stream>>>(QKV, QKV+(size_t)BL*DENC, QKV+(size_t)2*BL*DENC,
                                                         ATT, nullptr, 0.17677669529663687f);
        gemm16(ATT, wo, Xs, Xs, nullptr, DENC, DENC, 1);
        k_ln<128><<<BL,64,0,stream>>>(Xs, l2w, l2b, LN);
        gemm16(LN, w1, nullptr, H, nullptr, 2*DENC, DENC, 2);
        gemm16(H, w2, Xs, Xs, nullptr, DENC, 2*DENC, 1);
    };
    // decoder block: f16 MFMA flash
    auto block_dec = [&](float* Xs, const float* l1w, const float* l1b, const float* qkvw, const float* wo,
                        const float* l2w, const float* l2b, const float* w1, const float* w2){
        k_ln<128><<<BL,64,0,stream>>>(Xs, l1w, l1b, LN);
        gemm_qkv(LN, qkvw, DENC, 32, 5);
        k_mflash<32><<<dim3(B_*NHEADS,16),256,0,stream>>>((const f16*)QKV,
                                                          (const f16*)QKV + (size_t)BL*DENC,
                                                          (const f16*)QKV + (size_t)2*BL*DENC,
                                                          ATT, nullptr, 0.17677669529663687f);
        gemm16(ATT, wo, Xs, Xs, nullptr, DENC, DENC, 1);
        k_ln<128><<<BL,64,0,stream>>>(Xs, l2w, l2b, LN);
        gemm16(LN, w1, nullptr, H, nullptr, 2*DENC, DENC, 2);
        gemm16(H, w2, Xs, Xs, nullptr, DENC, 2*DENC, 1);
    };
    auto block_main = [&](float* Xs, const float* l1w, const float* l1b, const float* qkvw, const float* wo,
                        const float* l2w, const float* l2b, const float* w1, const float* w2){
        k_ln<256><<<BL,64,0,stream>>>(Xs, l1w, l1b, LN);
        gemm_qkv(LN, qkvw, DMAIN, 64, 5);
        k_mflash<64><<<dim3(B_*NHEADS,16),256,0,stream>>>((const f16*)QKV,
                                                          (const f16*)QKV + (size_t)BL*DMAIN,
                                                          (const f16*)QKV + (size_t)2*BL*DMAIN,
                                                          ATT, COUNTS, 0.125f);
        gemm16(ATT, wo, Xs, Xs, nullptr, DMAIN, DMAIN, 1);
        k_ln<256><<<BL,64,0,stream>>>(Xs, l2w, l2b, LN);
        gemm16(LN, w1, nullptr, H, nullptr, 2*DMAIN, DMAIN, 2);
        gemm16(H, w2, Xs, Xs, nullptr, DMAIN, 2*DMAIN, 1);
    };

    // ---- embed + encoder ----
    k_embed<<<BL*DENC/256, 256, 0, stream>>>(byte_ids, embed, X);
    for (int i = 0; i < 3; i++)
        block_enc(X, enc_ln1w + i*DENC, enc_ln1b + i*DENC, enc_qkv + (size_t)i*3*DENC*DENC,
                 enc_wo + (size_t)i*DENC*DENC, enc_ln2w + i*DENC, enc_ln2b + i*DENC,
                 enc_w1 + (size_t)i*2*DENC*DENC, enc_w2 + (size_t)i*2*DENC*DENC);

    // ---- routing (f32) ----
    gemm32(X, wq, ATT, DENC, DENC);
    gemm32(X, wk, TMP, DENC, DENC);
    k_router<<<BL, 64, 0, stream>>>(ATT, TMP, P, BH);
    k_seq<<<B_, 64, 0, stream>>>(BH, CIDX, DEST, COUNTS);
    k_zeroinit<<<BL*DENC/256, 256, 0, stream>>>(COMP, PCOMP, ACC);
    k_scatter<<<BL, 128, 0, stream>>>(X, P, DEST, BH, COMP, PCOMP);
    k_reduce<<<8, 256, 0, stream>>>(P, BH, ACC);

    // ---- main stack on compressed (f16 MFMA) ----
    gemm16(COMP, proj_up, nullptr, Z, nullptr, DMAIN, DENC, 0);
    for (int i = 0; i < 6; i++)
        block_main(Z, main_ln1w + i*DMAIN, main_ln1b + i*DMAIN, main_qkv + (size_t)i*3*DMAIN*DMAIN,
                 main_wo + (size_t)i*DMAIN*DMAIN, main_ln2w + i*DMAIN, main_ln2b + i*DMAIN,
                 main_w1 + (size_t)i*2*DMAIN*DMAIN, main_w2 + (size_t)i*2*DMAIN*DMAIN);
    gemm16(Z, proj_dn, nullptr, ZDN, nullptr, DENC, DMAIN, 0);

    // ---- EMA + dechunk combine ----
    k_ema2<<<256, 256, 0, stream>>>(ZDN, PCOMP, ZBAR);
    k_combine<<<BL*DENC/256, 256, 0, stream>>>(X, ZBAR, CIDX);

    // ---- decoder (f16 MFMA attention) ----
    for (int i = 0; i < 3; i++)
        block_dec(X, dec_ln1w + i*DENC, dec_ln1b + i*DENC, dec_qkv + (size_t)i*3*DENC*DENC,
                 dec_wo + (size_t)i*DENC*DENC, dec_ln2w + i*DENC, dec_ln2b + i*DENC,
                 dec_w1 + (size_t)i*2*DENC*DENC, dec_w2 + (size_t)i*2*DENC*DENC);

    // ---- final LN + tied head + loss ----
    k_ln<128><<<BL,64,0,stream>>>(X, norm_w, norm_b, LN);
    gemm16(LN, embed, nullptr, nullptr, d_out, VOCAB, DENC, 3);
    k_loss<<<1,1,0,stream>>>(ACC, d_out, FLAG);
}

// Round 7
// 1402.578 us; speedup vs baseline: 3.9996x; 1.5126x over previous
//
#include <hip/hip_runtime.h>
#include <hip/hip_bf16.h>

#define B_ 8
#define L_ 1024
#define BL (B_*L_)
#define DENC 128
#define DMAIN 256
#define VOCAB 260
#define NHEADS 4

typedef __hip_bfloat16 bf16;
typedef _Float16 f16;
typedef f16 half8 __attribute__((ext_vector_type(8)));
typedef float f32x4 __attribute__((ext_vector_type(4)));

// ---------------- dtype detector ----------------
__global__ __launch_bounds__(64) void k_detect(const void* __restrict__ emb, int* __restrict__ flag){
    int lane = threadIdx.x;
    const unsigned short* u = (const unsigned short*)emb;
    int bad = 0;
    #pragma unroll
    for (int j = 0; j < 4; j++){
        unsigned short h = u[lane + 64*j];
        bf16 t = *(const bf16*)&h;
        float v = __bfloat162float(t);
        if (!(fabsf(v) < 1e4f)) bad++;
    }
    #pragma unroll
    for (int o = 32; o >= 1; o >>= 1) bad += __shfl_xor(bad, o);
    if (lane == 0) flag[0] = (bad == 0) ? 1 : 0;
}

// ---------------- fused convert of all 31 float inputs ----------------
struct CvtArgs {
    const void* src[31];
    unsigned offs[32];
};
__global__ void k_cvt_all(CvtArgs a, float* __restrict__ dst, int total, const int* __restrict__ flag){
    int isbf = flag[0];
    for (int i = blockIdx.x*256 + threadIdx.x; i < total; i += gridDim.x*256){
        int lo = 0, hi = 30;
        while (lo < hi){ int mid = (lo+hi+1)>>1; if (a.offs[mid] <= (unsigned)i) lo = mid; else hi = mid-1; }
        int j = i - (int)a.offs[lo];
        dst[i] = isbf ? __bfloat162float(((const bf16*)a.src[lo])[j])
                      : ((const float*)a.src[lo])[j];
    }
}

// ---------------- embed gather ----------------
__global__ void k_embed(const int* __restrict__ ids, const float* __restrict__ emb, float* __restrict__ x){
    int i = blockIdx.x*256 + threadIdx.x;
    int row = i >> 7, d = i & 127;
    x[i] = emb[ids[row]*DENC + d];
}

// ---------------- layernorm: 256-thread block, wave per row ----------------
template<int D>
__global__ __launch_bounds__(256) void k_ln(const float* __restrict__ x, const float* __restrict__ w,
                                            const float* __restrict__ b, float* __restrict__ y){
    int row = blockIdx.x*4 + (threadIdx.x >> 6);
    int lane = threadIdx.x & 63;
    const float* xr = x + (size_t)row*D;
    float v[D/64];
    float s = 0.f;
    #pragma unroll
    for (int j=0;j<D/64;j++){ v[j] = xr[lane + j*64]; s += v[j]; }
    #pragma unroll
    for (int o=32;o>=1;o>>=1) s += __shfl_xor(s,o);
    float mu = s / (float)D;
    float s2 = 0.f;
    #pragma unroll
    for (int j=0;j<D/64;j++){ float dd = v[j]-mu; s2 += dd*dd; }
    #pragma unroll
    for (int o=32;o>=1;o>>=1) s2 += __shfl_xor(s2,o);
    float inv = rsqrtf(s2/(float)D + 1e-5f);
    float* yr = y + (size_t)row*D;
    #pragma unroll
    for (int j=0;j<D/64;j++){
        int d = lane + j*64;
        yr[d] = (v[j]-mu)*inv*w[d] + b[d];
    }
}

// ---------------- f32 vector GEMM: fused wq/wk (router only) ----------------
#define GBM 64
#define GBN 64
#define GBK 32
__global__ __launch_bounds__(256) void k_gemm2(const float* __restrict__ A, const float* __restrict__ Wq,
        const float* __restrict__ Wk, float* __restrict__ Cq, float* __restrict__ Ck, int K)
{
    __shared__ float As[GBK][GBM+4];
    __shared__ float Ws[GBK][GBN+4];
    int tid = threadIdx.x;
    int bm = blockIdx.y * GBM;
    int bn = blockIdx.x * GBN;
    int tx = tid & 15, ty = tid >> 4;
    float acc[4][4] = {};
    for (int k0 = 0; k0 < K; k0 += GBK){
        #pragma unroll
        for (int i = tid; i < GBM*GBK; i += 256){
            int m = i >> 5, kk = i & 31;
            As[kk][m] = A[(size_t)(bm+m)*K + k0 + kk];
        }
        #pragma unroll
        for (int i = tid; i < GBN*GBK; i += 256){
            int n = i >> 5, kk = i & 31;
            int gn = bn + n;
            const float* W = (gn < 128) ? Wq : Wk;
            int wr = gn & 127;
            Ws[kk][n] = W[(size_t)wr*K + k0 + kk];
        }
        __syncthreads();
        #pragma unroll
        for (int kk = 0; kk < GBK; kk++){
            float a0[4], w0[4];
            *(float4*)a0 = *(const float4*)&As[kk][ty*4];
            *(float4*)w0 = *(const float4*)&Ws[kk][tx*4];
            #pragma unroll
            for (int i=0;i<4;i++)
                #pragma unroll
                for (int j=0;j<4;j++) acc[i][j] += a0[i]*w0[j];
        }
        __syncthreads();
    }
    #pragma unroll
    for (int i=0;i<4;i++){
        int m = bm + ty*4 + i;
        #pragma unroll
        for (int j=0;j<4;j++){
            int n = bn + tx*4 + j;
            float* C = (n < 128) ? Cq : Ck;
            C[(size_t)m*128 + (n & 127)] = acc[i][j];
        }
    }
}

// ---------------- f16 MFMA GEMM, 64x64 tile (4 waves, 2x2 MFMAs each) ----------------
// modes: 0 plain, 1 +R, 2 gelu, 3 out-store, 5 split-head QKV f16 (V transposed)
__global__ __launch_bounds__(256) void k_mgemm(const float* __restrict__ A, const float* __restrict__ W,
        const float* __restrict__ R, float* __restrict__ C, void* __restrict__ OutRaw,
        const int* __restrict__ flag, int M, int N, int K, int mode,
        f16* __restrict__ Qd, f16* __restrict__ Kd, f16* __restrict__ Vd,
        int dShift, int dhShift)
{
    __shared__ half8 As[4][64];
    __shared__ half8 Ws[4][64];
    int tid = threadIdx.x;
    int wave = tid >> 6, lane = tid & 63;
    int wr = wave >> 1, wc = wave & 1;
    int quad = lane >> 4, l15 = lane & 15;
    int bm = blockIdx.y * 64;
    int bn = blockIdx.x * 64;

    f32x4 acc[2][2] = {};

    int srow = tid >> 2;          // 0..63
    int sc8  = tid & 3;           // which 8-float chunk of the 32-wide K tile
    const float* ap0 = A + (size_t)(bm + srow)*K + sc8*8;
    int gn = bn + srow;
    const float* wp0 = W + (size_t)gn*K + sc8*8;
    bool wok = (gn < N);

    for (int k0 = 0; k0 < K; k0 += 32){
        __syncthreads();
        {
            const float* ap = ap0 + k0;
            float4 u0 = *(const float4*)(ap);
            float4 u1 = *(const float4*)(ap+4);
            half8 h0;
            h0[0]=(f16)u0.x; h0[1]=(f16)u0.y; h0[2]=(f16)u0.z; h0[3]=(f16)u0.w;
            h0[4]=(f16)u1.x; h0[5]=(f16)u1.y; h0[6]=(f16)u1.z; h0[7]=(f16)u1.w;
            As[sc8][srow] = h0;
            half8 g0 = (half8)(f16)0.f;
            if (wok){
                const float* wp = wp0 + k0;
                float4 v0 = *(const float4*)(wp);
                float4 v1 = *(const float4*)(wp+4);
                g0[0]=(f16)v0.x; g0[1]=(f16)v0.y; g0[2]=(f16)v0.z; g0[3]=(f16)v0.w;
                g0[4]=(f16)v1.x; g0[5]=(f16)v1.y; g0[6]=(f16)v1.z; g0[7]=(f16)v1.w;
            }
            Ws[sc8][srow] = g0;
        }
        __syncthreads();

        half8 af[2], wf[2];
        #pragma unroll
        for (int i=0;i<2;i++) af[i] = As[quad][wr*32 + i*16 + l15];
        #pragma unroll
        for (int j=0;j<2;j++) wf[j] = Ws[quad][wc*32 + j*16 + l15];
        #pragma unroll
        for (int i=0;i<2;i++)
            #pragma unroll
            for (int j=0;j<2;j++)
                acc[i][j] = __builtin_amdgcn_mfma_f32_16x16x32_f16(af[i], wf[j], acc[i][j], 0, 0, 0);
    }

    #pragma unroll
    for (int j=0;j<2;j++){
        int n = bn + wc*32 + j*16 + l15;
        if (n >= N) continue;
        #pragma unroll
        for (int i=0;i<2;i++){
            #pragma unroll
            for (int r=0;r<4;r++){
                int m = bm + wr*32 + i*16 + quad*4 + r;
                float v = acc[i][j][r];
                if (mode == 5){
                    int which = n >> dShift;
                    int rem = n & ((1<<dShift)-1);
                    int hh = rem >> dhShift;
                    int dd = rem & ((1<<dhShift)-1);
                    int bb = m >> 10, tt = m & 1023;
                    int Hn = 1 << (dShift - dhShift);
                    f16* dst = (which==0) ? Qd : ((which==1) ? Kd : Vd);
                    if (which == 2)
                        dst[((((size_t)bb*Hn + hh) << dhShift) + dd)*L_ + tt] = (f16)v;  // V^T
                    else
                        dst[((((size_t)bb*Hn + hh)*L_ + tt) << dhShift) + dd] = (f16)v;
                    continue;
                }
                size_t off = (size_t)m*N + n;
                if (mode == 1) v += R[off];
                else if (mode == 2) v = 0.5f*v*(1.0f + erff(v*0.70710678118654752f));
                if (mode == 3){
                    if (flag[0]) ((bf16*)OutRaw)[off] = __float2bfloat16(v);
                    else         ((float*)OutRaw)[off] = v;
                } else C[off] = v;
            }
        }
    }
}

// ---------------- MFMA f16 flash (all attention) ----------------
// block = 4 waves, BQ=64 (wave w owns q rows 16w..16w+15), BK=64
template<int DH>
__global__ __launch_bounds__(256) void k_mflash(const f16* __restrict__ Qh, const f16* __restrict__ Kh,
        const f16* __restrict__ Vt, float* __restrict__ out, const int* __restrict__ counts,
        float scale)
{
    constexpr int BQ = 64, BK = 64;
    constexpr int RS = DH + 8;
    constexpr int PS = BK + 8;
    __shared__ f16 sQ[BQ*RS];
    __shared__ f16 sK[BK*RS];
    __shared__ f16 sVt[DH*PS];
    __shared__ f16 sP[BQ*PS];

    int x = blockIdx.x, b = x >> 2, h = x & 3;
    int yy = blockIdx.y;
    int qt = (yy < 8) ? yy : 23 - yy;
    int q0 = qt * BQ;
    int tid = threadIdx.x;
    int wv = tid >> 6, lane = tid & 63;
    int quad = lane >> 4, l15 = lane & 15;

    const f16* Qb = Qh + (size_t)x*L_*DH;
    const f16* Kb = Kh + (size_t)x*L_*DH;
    const f16* Vb = Vt + (size_t)x*DH*L_;
    int kcap = counts ? counts[b] : L_;
    int klen = min(kcap, q0 + BQ);

    for (int i = tid; i < BQ*DH/8; i += 256){
        int r = (8*i)/DH, c = (8*i)%DH;
        *(half8*)&sQ[r*RS + c] = *(const half8*)&Qb[(size_t)(q0+r)*DH + c];
    }

    float m[4], l[4];
    #pragma unroll
    for (int r=0;r<4;r++){ m[r] = -1e30f; l[r] = 0.f; }
    f32x4 accO[DH/16] = {};

    for (int k0 = 0; k0 < klen; k0 += BK){
        __syncthreads();
        for (int i = tid; i < BK*DH/8; i += 256){
            int r = (8*i)/DH, c = (8*i)%DH;
            *(half8*)&sK[r*RS + c] = *(const half8*)&Kb[(size_t)(k0+r)*DH + c];
        }
        for (int i = tid; i < DH*BK/8; i += 256){
            int r = (8*i)/BK, c = (8*i)%BK;
            *(half8*)&sVt[r*PS + c] = *(const half8*)&Vb[(size_t)r*L_ + k0 + c];
        }
        __syncthreads();

        half8 af[DH/32];
        #pragma unroll
        for (int ds=0; ds<DH/32; ds++)
            af[ds] = *(const half8*)&sQ[(16*wv + l15)*RS + quad*8 + 32*ds];
        f32x4 accS[4] = {};
        #pragma unroll
        for (int t=0;t<4;t++){
            #pragma unroll
            for (int ds=0; ds<DH/32; ds++){
                half8 bf = *(const half8*)&sK[(16*t + l15)*RS + quad*8 + 32*ds];
                accS[t] = __builtin_amdgcn_mfma_f32_16x16x32_f16(af[ds], bf, accS[t], 0, 0, 0);
            }
        }

        #pragma unroll
        for (int r=0;r<4;r++){
            int qrow = q0 + 16*wv + quad*4 + r;
            float sv[4];
            #pragma unroll
            for (int t=0;t<4;t++){
                float v = accS[t][r]*scale;
                int kp = k0 + 16*t + l15;
                if (kp > qrow || kp >= kcap) v = -1e30f;
                sv[t] = v;
            }
            float rm = fmaxf(fmaxf(sv[0],sv[1]), fmaxf(sv[2],sv[3]));
            rm = fmaxf(rm, __shfl_xor(rm, 1));
            rm = fmaxf(rm, __shfl_xor(rm, 2));
            rm = fmaxf(rm, __shfl_xor(rm, 4));
            rm = fmaxf(rm, __shfl_xor(rm, 8));
            float mn = fmaxf(m[r], rm);
            float al = __expf(m[r] - mn);
            float p0 = __expf(sv[0]-mn), p1 = __expf(sv[1]-mn);
            float p2 = __expf(sv[2]-mn), p3 = __expf(sv[3]-mn);
            float rs = p0+p1+p2+p3;
            rs += __shfl_xor(rs, 1);
            rs += __shfl_xor(rs, 2);
            rs += __shfl_xor(rs, 4);
            rs += __shfl_xor(rs, 8);
            l[r] = l[r]*al + rs;
            m[r] = mn;
            #pragma unroll
            for (int dt=0; dt<DH/16; dt++) accO[dt][r] *= al;
            int prow = 16*wv + quad*4 + r;
            sP[prow*PS + 16*0 + l15] = (f16)p0;
            sP[prow*PS + 16*1 + l15] = (f16)p1;
            sP[prow*PS + 16*2 + l15] = (f16)p2;
            sP[prow*PS + 16*3 + l15] = (f16)p3;
        }

        half8 pf[2];
        #pragma unroll
        for (int ks=0; ks<2; ks++)
            pf[ks] = *(const half8*)&sP[(16*wv + l15)*PS + quad*8 + 32*ks];
        #pragma unroll
        for (int dt=0; dt<DH/16; dt++){
            #pragma unroll
            for (int ks=0; ks<2; ks++){
                half8 bv = *(const half8*)&sVt[(16*dt + l15)*PS + quad*8 + 32*ks];
                accO[dt] = __builtin_amdgcn_mfma_f32_16x16x32_f16(pf[ks], bv, accO[dt], 0, 0, 0);
            }
        }
    }

    #pragma unroll
    for (int r=0;r<4;r++){
        float inv = 1.0f / l[r];
        int qrow = q0 + 16*wv + quad*4 + r;
        #pragma unroll
        for (int dt=0; dt<DH/16; dt++){
            int d = 16*dt + l15;
            out[((size_t)b*L_ + qrow)*(NHEADS*DH) + h*DH + d] = accO[dt][r]*inv;
        }
    }
}

// ---------------- router ----------------
__global__ __launch_bounds__(64) void k_router(const float* __restrict__ Q, const float* __restrict__ Kr,
        float* __restrict__ p, float* __restrict__ bh)
{
    int idx = blockIdx.x;
    int t = idx & (L_-1);
    int lane = threadIdx.x;
    float pv;
    if (t == 0){ pv = 1.0f; }
    else {
        const float* qr = Q  + (size_t)idx*DENC;
        const float* kr = Kr + (size_t)(idx-1)*DENC;
        float qq=0.f, kk=0.f, qk=0.f;
        #pragma unroll
        for (int j=0;j<2;j++){
            float qv = qr[lane + j*64], kv = kr[lane + j*64];
            qq += qv*qv; kk += kv*kv; qk += qv*kv;
        }
        #pragma unroll
        for (int o=32;o>=1;o>>=1){ qq += __shfl_xor(qq,o); kk += __shfl_xor(kk,o); qk += __shfl_xor(qk,o); }
        float cosv = qk / (fmaxf(sqrtf(qq),1e-12f)*fmaxf(sqrtf(kk),1e-12f));
        pv = 0.5f*(1.0f - cosv);
        pv = fminf(fmaxf(pv, 0.0f), 1.0f);
    }
    if (lane == 0){ p[idx] = pv; bh[idx] = (pv >= 0.5f) ? 1.0f : 0.0f; }
}

// ---------------- per-batch cumsum via wave scan ----------------
__global__ __launch_bounds__(64) void k_seq(const float* __restrict__ bh, int* __restrict__ cidx,
                      int* __restrict__ dest, int* __restrict__ counts){
    int b = blockIdx.x;
    int lane = threadIdx.x;
    int base = b*L_ + lane*16;
    int h[16];
    int cnt = 0;
    #pragma unroll
    for (int j=0;j<16;j++){ h[j] = bh[base+j] > 0.5f; cnt += h[j]; }
    int inc = cnt;
    #pragma unroll
    for (int o=1;o<64;o<<=1){ int nb = __shfl_up(inc, o); if (lane >= o) inc += nb; }
    int run = inc - cnt;
    #pragma unroll
    for (int j=0;j<16;j++){
        run += h[j];
        int ci = run - 1; if (ci < 0) ci = 0;
        cidx[base+j] = ci;
        dest[base+j] = h[j] ? (run-1) : L_;
    }
    if (lane == 63) counts[b] = inc;
}

__global__ void k_zeroinit(float* __restrict__ comp, float* __restrict__ pcomp, float* __restrict__ acc){
    int i = blockIdx.x*256 + threadIdx.x;
    comp[i] = 0.f;
    if (i < BL) pcomp[i] = 0.f;
    if (i < 8) acc[i] = 0.f;
}

__global__ void k_scatter(const float* __restrict__ x, const float* __restrict__ p,
        const int* __restrict__ dest, const float* __restrict__ bh,
        float* __restrict__ comp, float* __restrict__ pcomp)
{
    int i = blockIdx.x;
    int d = threadIdx.x;
    int b = i >> 10;
    if (bh[i] > 0.5f){
        int ds = dest[i];
        comp[((size_t)b*L_ + ds)*DENC + d] = x[(size_t)i*DENC + d];
        if (d == 0) pcomp[b*L_ + ds] = p[i];
    }
}

__global__ __launch_bounds__(256) void k_reduce(const float* __restrict__ p, const float* __restrict__ bh,
                                                float* __restrict__ acc){
    __shared__ float sp[256], sb[256];
    int tid = threadIdx.x;
    float s1=0.f, s2=0.f;
    for (int i = blockIdx.x*256 + tid; i < BL; i += gridDim.x*256){ s1 += p[i]; s2 += bh[i]; }
    sp[tid]=s1; sb[tid]=s2; __syncthreads();
    for (int o=128;o>=1;o>>=1){ if (tid<o){ sp[tid]+=sp[tid+o]; sb[tid]+=sb[tid+o]; } __syncthreads(); }
    if (tid==0){ atomicAdd(&acc[0], sp[0]); atomicAdd(&acc[1], sb[0]); }
}

// ---------------- chunk EMA: 3-phase wave scan ----------------
__global__ __launch_bounds__(256) void k_ema2(const float* __restrict__ z, const float* __restrict__ pcomp,
                                              float* __restrict__ zbar){
    __shared__ float sp[L_];
    int blk = blockIdx.x;
    int b = blk >> 5;
    int tid = threadIdx.x, wv = tid >> 6, lane = tid & 63;
    int d = ((blk & 31) << 2) + wv;
    for (int i = tid; i < L_; i += 256){
        float pc = pcomp[b*L_ + i];
        sp[i] = fminf(fmaxf(pc, 1e-4f), 1.0f - 1e-4f);
    }
    __syncthreads();
    const float* zb = z + ((size_t)b*L_)*DENC + d;
    int t0 = lane*16;
    float zv[16];
    #pragma unroll
    for (int i=0;i<16;i++) zv[i] = zb[(size_t)(t0+i)*DENC];
    float A = 1.f, Bv = 0.f;
    #pragma unroll
    for (int i=0;i<16;i++){
        int t = t0 + i;
        float pc = sp[t];
        float a  = (t==0) ? 0.f : (1.f - pc);
        float bb = (t==0) ? zv[i] : pc*zv[i];
        A = a*A;
        Bv = a*Bv + bb;
    }
    #pragma unroll
    for (int off=1; off<64; off<<=1){
        float Ap = __shfl_up(A, off);
        float Bp = __shfl_up(Bv, off);
        if (lane >= off){ Bv = A*Bp + Bv; A = A*Ap; }
    }
    float sin_ = __shfl_up(Bv, 1);
    if (lane == 0) sin_ = 0.f;
    float s = sin_;
    float* ob = zbar + ((size_t)b*L_)*DENC + d;
    #pragma unroll
    for (int i=0;i<16;i++){
        int t = t0 + i;
        float pc = sp[t];
        float a  = (t==0) ? 0.f : (1.f - pc);
        float bb = (t==0) ? zv[i] : pc*zv[i];
        s = a*s + bb;
        ob[(size_t)t*DENC] = s;
    }
}

__global__ void k_combine(float* __restrict__ x, const float* __restrict__ zbar, const int* __restrict__ cidx){
    int i = blockIdx.x*256 + threadIdx.x;
    int row = i >> 7, d = i & 127;
    int b = row >> 10;
    int ci = cidx[row];
    x[i] += zbar[((size_t)b*L_ + ci)*DENC + d];
}

__global__ void k_loss(const float* __restrict__ acc, void* __restrict__ out, const int* __restrict__ flag){
    float G = acc[0] / (float)BL;
    float F = acc[1] / (float)BL;
    float ratio = 1.2f*(5.0f*F*G + (1.0f-F)*(1.0f-G));
    if (flag[0]) ((bf16*)out)[(size_t)BL*VOCAB] = __float2bfloat16(ratio);
    else         ((float*)out)[(size_t)BL*VOCAB] = ratio;
}

// =========================================================================
extern "C" void kernel_launch(void* const* d_in, const int* in_sizes, int n_in,
                              void* d_out, int out_size, void* d_ws, size_t ws_size,
                              hipStream_t stream) {
    (void)out_size; (void)ws_size;
    const int* byte_ids = (const int*)d_in[0];

    float* ws = (float*)d_ws;
    size_t off = 0;
    int* FLAG = (int*)ws; off += 16;
    float* W32 = ws + off;

    k_detect<<<1, 64, 0, stream>>>(d_in[1], FLAG);

    CvtArgs ca;
    const float* w32[32];
    unsigned woff = 0;
    for (int i = 1; i < n_in && i < 32; i++){
        w32[i] = W32 + woff;
        ca.src[i-1] = d_in[i];
        ca.offs[i-1] = woff;
        woff += (unsigned)in_sizes[i];
    }
    ca.offs[31] = woff;
    k_cvt_all<<<2048, 256, 0, stream>>>(ca, W32, (int)woff, FLAG);
    off += woff;

    const float* embed    = w32[1];
    const float* wq       = w32[2];
    const float* wk       = w32[3];
    const float* proj_up  = w32[4];
    const float* proj_dn  = w32[5];
    const float* norm_w   = w32[6];
    const float* norm_b   = w32[7];
    const float* enc_ln1w = w32[8];
    const float* enc_ln1b = w32[9];
    const float* enc_qkv  = w32[10];
    const float* enc_wo   = w32[11];
    const float* enc_ln2w = w32[12];
    const float* enc_ln2b = w32[13];
    const float* enc_w1   = w32[14];
    const float* enc_w2   = w32[15];
    const float* main_ln1w= w32[16];
    const float* main_ln1b= w32[17];
    const float* main_qkv = w32[18];
    const float* main_wo  = w32[19];
    const float* main_ln2w= w32[20];
    const float* main_ln2b= w32[21];
    const float* main_w1  = w32[22];
    const float* main_w2  = w32[23];
    const float* dec_ln1w = w32[24];
    const float* dec_ln1b = w32[25];
    const float* dec_qkv  = w32[26];
    const float* dec_wo   = w32[27];
    const float* dec_ln2w = w32[28];
    const float* dec_ln2b = w32[29];
    const float* dec_w1   = w32[30];
    const float* dec_w2   = w32[31];

    float* X    = ws + off; off += (size_t)BL*DENC;
    float* LN   = ws + off; off += (size_t)BL*DMAIN;
    float* QKV  = ws + off; off += (size_t)BL*3*DMAIN;
    float* ATT  = ws + off; off += (size_t)BL*DMAIN;
    float* H    = ws + off; off += (size_t)BL*2*DMAIN;
    float* Z    = ws + off; off += (size_t)BL*DMAIN;
    float* COMP = ws + off; off += (size_t)BL*DENC;
    float* P    = ws + off; off += BL;
    float* BH   = ws + off; off += BL;
    float* PCOMP= ws + off; off += BL;
    float* ACC  = ws + off; off += 8;
    int* CIDX   = (int*)(ws + off); off += BL;
    int* DEST   = (int*)(ws + off); off += BL;
    int* COUNTS = (int*)(ws + off); off += 64;
    float* TMP  = H;
    float* ZDN  = QKV;
    float* ZBAR = QKV + (size_t)BL*DENC;

    auto gemm16 = [&](const float* A, const float* W, const float* R, float* C, void* Ob,
                    int N, int K, int mode){
        dim3 g((N+63)/64, BL/64);
        k_mgemm<<<g, 256, 0, stream>>>(A, W, R, C, Ob, FLAG, BL, N, K, mode,
                                       nullptr, nullptr, nullptr, 0, 0);
    };
    auto gemm_qkv = [&](const float* A, const float* W, int D, int dh){
        int N = 3*D;
        int dS = (D == 128) ? 7 : 8;
        int dhS = (dh == 32) ? 5 : 6;
        f16* Qh = (f16*)QKV;
        f16* Kh = (f16*)QKV + (size_t)BL*D;
        f16* Vh = (f16*)QKV + (size_t)2*BL*D;
        dim3 g((N+63)/64, BL/64);
        k_mgemm<<<g, 256, 0, stream>>>(A, W, nullptr, nullptr, nullptr, FLAG, BL, N, D, 5,
                                       Qh, Kh, Vh, dS, dhS);
    };

    // 128-dim block (encoder + decoder): full f16
    auto block128 = [&](float* Xs, const float* l1w, const float* l1b, const float* qkvw, const float* wo,
                        const float* l2w, const float* l2b, const float* w1, const float* w2){
        k_ln<128><<<BL/4,256,0,stream>>>(Xs, l1w, l1b, LN);
        gemm_qkv(LN, qkvw, DENC, 32);
        k_mflash<32><<<dim3(B_*NHEADS,16),256,0,stream>>>((const f16*)QKV,
                                                          (const f16*)QKV + (size_t)BL*DENC,
                                                          (const f16*)QKV + (size_t)2*BL*DENC,
                                                          ATT, nullptr, 0.17677669529663687f);
        gemm16(ATT, wo, Xs, Xs, nullptr, DENC, DENC, 1);
        k_ln<128><<<BL/4,256,0,stream>>>(Xs, l2w, l2b, LN);
        gemm16(LN, w1, nullptr, H, nullptr, 2*DENC, DENC, 2);
        gemm16(H, w2, Xs, Xs, nullptr, DENC, 2*DENC, 1);
    };
    auto block_main = [&](float* Xs, const float* l1w, const float* l1b, const float* qkvw, const float* wo,
                        const float* l2w, const float* l2b, const float* w1, const float* w2){
        k_ln<256><<<BL/4,256,0,stream>>>(Xs, l1w, l1b, LN);
        gemm_qkv(LN, qkvw, DMAIN, 64);
        k_mflash<64><<<dim3(B_*NHEADS,16),256,0,stream>>>((const f16*)QKV,
                                                          (const f16*)QKV + (size_t)BL*DMAIN,
                                                          (const f16*)QKV + (size_t)2*BL*DMAIN,
                                                          ATT, COUNTS, 0.125f);
        gemm16(ATT, wo, Xs, Xs, nullptr, DMAIN, DMAIN, 1);
        k_ln<256><<<BL/4,256,0,stream>>>(Xs, l2w, l2b, LN);
        gemm16(LN, w1, nullptr, H, nullptr, 2*DMAIN, DMAIN, 2);
        gemm16(H, w2, Xs, Xs, nullptr, DMAIN, 2*DMAIN, 1);
    };

    // ---- embed + encoder ----
    k_embed<<<BL*DENC/256, 256, 0, stream>>>(byte_ids, embed, X);
    for (int i = 0; i < 3; i++)
        block128(X, enc_ln1w + i*DENC, enc_ln1b + i*DENC, enc_qkv + (size_t)i*3*DENC*DENC,
                 enc_wo + (size_t)i*DENC*DENC, enc_ln2w + i*DENC, enc_ln2b + i*DENC,
                 enc_w1 + (size_t)i*2*DENC*DENC, enc_w2 + (size_t)i*2*DENC*DENC);

    // ---- routing (f32, fused wq/wk) ----
    k_gemm2<<<dim3(4, BL/64), 256, 0, stream>>>(X, wq, wk, ATT, TMP, DENC);
    k_router<<<BL, 64, 0, stream>>>(ATT, TMP, P, BH);
    k_seq<<<B_, 64, 0, stream>>>(BH, CIDX, DEST, COUNTS);
    k_zeroinit<<<BL*DENC/256, 256, 0, stream>>>(COMP, PCOMP, ACC);
    k_scatter<<<BL, 128, 0, stream>>>(X, P, DEST, BH, COMP, PCOMP);
    k_reduce<<<8, 256, 0, stream>>>(P, BH, ACC);

    // ---- main stack on compressed (f16 MFMA) ----
    gemm16(COMP, proj_up, nullptr, Z, nullptr, DMAIN, DENC, 0);
    for (int i = 0; i < 6; i++)
        block_main(Z, main_ln1w + i*DMAIN, main_ln1b + i*DMAIN, main_qkv + (size_t)i*3*DMAIN*DMAIN,
                 main_wo + (size_t)i*DMAIN*DMAIN, main_ln2w + i*DMAIN, main_ln2b + i*DMAIN,
                 main_w1 + (size_t)i*2*DMAIN*DMAIN, main_w2 + (size_t)i*2*DMAIN*DMAIN);
    gemm16(Z, proj_dn, nullptr, ZDN, nullptr, DENC, DMAIN, 0);

    // ---- EMA + dechunk combine ----
    k_ema2<<<256, 256, 0, stream>>>(ZDN, PCOMP, ZBAR);
    k_combine<<<BL*DENC/256, 256, 0, stream>>>(X, ZBAR, CIDX);

    // ---- decoder ----
    for (int i = 0; i < 3; i++)
        block128(X, dec_ln1w + i*DENC, dec_ln1b + i*DENC, dec_qkv + (size_t)i*3*DENC*DENC,
                 dec_wo + (size_t)i*DENC*DENC, dec_ln2w + i*DENC, dec_ln2b + i*DENC,
                 dec_w1 + (size_t)i*2*DENC*DENC, dec_w2 + (size_t)i*2*DENC*DENC);

    // ---- final LN + tied head + loss ----
    k_ln<128><<<BL/4,256,0,stream>>>(X, norm_w, norm_b, LN);
    gemm16(LN, embed, nullptr, nullptr, d_out, VOCAB, DENC, 3);
    k_loss<<<1,1,0,stream>>>(ACC, d_out, FLAG);
}